// Round 13
// baseline (209.253 us; speedup 1.0000x reference)
//
#include <hip/hip_runtime.h>
#include <hip/hip_bf16.h>
#include <stdint.h>

#define H_ 8
#define NS_ 2048
#define C_ 512
#define HD_ 64
#define SCALE_ 0.125f
#define NEG_ -10000.0f
#define LOG2E_ 1.4426950408889634f
#define MFIX_ 4.0f

typedef _Float16 f16x8_t __attribute__((ext_vector_type(8)));
typedef _Float16 f16x4_t __attribute__((ext_vector_type(4)));
typedef __fp16 h16x2_t __attribute__((ext_vector_type(2)));   // cvt_pkrtz ret type
typedef float f32x4_t __attribute__((ext_vector_type(4)));

#define MFMAH(a, b, c) __builtin_amdgcn_mfma_f32_16x16x32_f16(a, b, c, 0, 0, 0)

__device__ inline f16x8_t load_h8(const _Float16* p) {
    return *reinterpret_cast<const f16x8_t*>(p);
}

// async global->LDS, 16B per lane; LDS dest = uniform base + lane*16
__device__ inline void gload_lds16(const void* g, void* l) {
    __builtin_amdgcn_global_load_lds(
        (const __attribute__((address_space(1))) unsigned int*)g,
        (__attribute__((address_space(3))) unsigned int*)l, 16, 0, 0);
}

__device__ inline unsigned orderF(float v) {
    unsigned u = __float_as_uint(v);
    return (u & 0x80000000u) ? ~u : (u | 0x80000000u);
}
__device__ inline unsigned long long packVR(float v, int idx) {
    return ((unsigned long long)orderF(v) << 32) | (unsigned)(~idx);
}
__device__ inline unsigned long long max64(unsigned long long a, unsigned long long b) {
    return a > b ? a : b;
}
__device__ inline unsigned long long shflx64(unsigned long long x, int m) {
    unsigned lo = (unsigned)x, hi = (unsigned)(x >> 32);
    lo = __shfl_xor(lo, m, 64);
    hi = __shfl_xor(hi, m, 64);
    return ((unsigned long long)hi << 32) | lo;
}

// ---------------------------------------------------------------------------
// K0: all four 512x512 weights -> f16 hi/lo splits in one launch.
// ---------------------------------------------------------------------------
__global__ __launch_bounds__(256) void wsplit4(
        const float* __restrict__ w0, const float* __restrict__ w1,
        const float* __restrict__ w2, const float* __restrict__ w3,
        _Float16* __restrict__ hi, _Float16* __restrict__ lo)
{
    const int i = blockIdx.x * 256 + threadIdx.x;            // 65536 float4 / W
    const int y = blockIdx.y;
    const float* src = (y == 0) ? w0 : (y == 1) ? w1 : (y == 2) ? w2 : w3;
    const float4 v = reinterpret_cast<const float4*>(src)[i];
    f16x4_t hv, lv;
    hv[0] = (_Float16)v.x; hv[1] = (_Float16)v.y;
    hv[2] = (_Float16)v.z; hv[3] = (_Float16)v.w;
    lv[0] = (_Float16)(v.x - (float)hv[0]);
    lv[1] = (_Float16)(v.y - (float)hv[1]);
    lv[2] = (_Float16)(v.z - (float)hv[2]);
    lv[3] = (_Float16)(v.w - (float)hv[3]);
    const size_t o = ((size_t)y << 16) + i;                  // float4 index
    reinterpret_cast<f16x4_t*>(hi)[o] = hv;
    reinterpret_cast<f16x4_t*>(lo)[o] = lv;
}

// ---------------------------------------------------------------------------
// K1: projection GEMM (q/k/v via grid.z). 3-term split-f16 MFMA (~fp32).
// z<2: hi/lo split out [bh][n][d]; z==2: V tiled [bh][key>>5][d][k'] with
// k' = ((key>>2)&3)<<3 | ((key>>4)&1)<<2 | (key&3)
// (chosen so attn_pv's in-register P fragment k-slot quad*8+i hits its keys).
// [round-10 form: on-the-fly A split; the asplit pre-pass (round 12) was a
//  net loss -- proj_gemm is bound by the cold HBM read of q/k/v, and the
//  extra pass added traffic without removing it.]
// ---------------------------------------------------------------------------
__global__ __launch_bounds__(256) void proj_gemm(
        const float* __restrict__ qin, const float* __restrict__ kin,
        const float* __restrict__ vin,
        const _Float16* __restrict__ wHall, const _Float16* __restrict__ wLall,
        _Float16* __restrict__ qhi, _Float16* __restrict__ qlo,
        _Float16* __restrict__ khi, _Float16* __restrict__ klo,
        _Float16* __restrict__ vT)
{
    __shared__ __attribute__((aligned(16))) _Float16 Wsh[2][2][4096];  // 32 KB
    const int zz = blockIdx.z;
    const float* A32 = (zz == 0) ? qin : (zz == 1) ? kin : vin;
    const _Float16* Wh = wHall + ((size_t)zz << 18);
    const _Float16* Wl = wLall + ((size_t)zz << 18);
    const int t = threadIdx.x, w = t >> 6, lane = t & 63;
    const int m16 = lane & 15, quad = lane >> 4;
    const int bm = blockIdx.x << 7, bn = blockIdx.y << 6;
    const int r0 = bm + (w << 5) + m16, r1 = r0 + 16;
    const int krow = lane >> 3, kblk = (lane & 7) ^ (krow & 7);
    const int e = m16 & 7;
    const int s00 = (quad ^ e) << 3, s01 = ((4 + quad) ^ e) << 3;
    const f32x4_t z = {0.f, 0.f, 0.f, 0.f};
    f32x4_t acc[2][4];
    #pragma unroll
    for (int rs = 0; rs < 2; rs++)
        #pragma unroll
        for (int tl = 0; tl < 4; tl++) acc[rs][tl] = z;

    auto stageW = [&](int buf, int kc) {
        #pragma unroll
        for (int ci = 0; ci < 4; ci++) {
            const int pp = (w << 2) + ci;
            const int s = pp >> 3, pj = pp & 7;
            const _Float16* src = (s ? Wl : Wh)
                + (size_t)(bn + (pj << 3) + krow) * C_ + kc + (kblk << 3);
            gload_lds16(src, &Wsh[buf][s][pj << 9]);
        }
    };
    auto loadA = [&](int kc, f16x8_t* d) {
        #pragma unroll
        for (int rs = 0; rs < 2; rs++) {
            const float* pr = A32 + (size_t)(rs ? r1 : r0) * C_ + kc + (quad << 3);
            #pragma unroll
            for (int seg = 0; seg < 2; seg++) {
                f16x8_t hv, lv;
                #pragma unroll
                for (int i = 0; i < 8; i++) {
                    const float x = pr[seg * 32 + i];
                    const _Float16 hh = (_Float16)x;
                    hv[i] = hh;
                    lv[i] = (_Float16)(x - (float)hh);
                }
                d[rs * 4 + seg] = hv;
                d[rs * 4 + seg + 2] = lv;
            }
        }
    };

    f16x8_t cA[8], nA[8];
    stageW(0, 0);
    loadA(0, cA);
    for (int ch = 0; ch < 8; ch++) {
        __syncthreads();
        if (ch + 1 < 8) {
            stageW((ch + 1) & 1, (ch + 1) << 6);
            loadA((ch + 1) << 6, nA);
        }
        const _Float16* W0 = Wsh[ch & 1][0];
        const _Float16* W1 = Wsh[ch & 1][1];
        #pragma unroll
        for (int tl = 0; tl < 4; tl++) {
            const int j64 = ((tl << 4) + m16) << 6;
            const f16x8_t bh0 = load_h8(&W0[j64 + s00]);
            const f16x8_t bh1 = load_h8(&W0[j64 + s01]);
            const f16x8_t bl0 = load_h8(&W1[j64 + s00]);
            const f16x8_t bl1 = load_h8(&W1[j64 + s01]);
            f32x4_t c0 = acc[0][tl];
            c0 = MFMAH(cA[0], bh0, c0); c0 = MFMAH(cA[1], bh1, c0);
            c0 = MFMAH(cA[2], bh0, c0); c0 = MFMAH(cA[3], bh1, c0);
            c0 = MFMAH(cA[0], bl0, c0); c0 = MFMAH(cA[1], bl1, c0);
            acc[0][tl] = c0;
            f32x4_t c1 = acc[1][tl];
            c1 = MFMAH(cA[4], bh0, c1); c1 = MFMAH(cA[5], bh1, c1);
            c1 = MFMAH(cA[6], bh0, c1); c1 = MFMAH(cA[7], bh1, c1);
            c1 = MFMAH(cA[4], bl0, c1); c1 = MFMAH(cA[5], bl1, c1);
            acc[1][tl] = c1;
        }
        #pragma unroll
        for (int i = 0; i < 8; i++) cA[i] = nA[i];
    }
    const int by = blockIdx.y;
    _Float16* o1 = (zz == 0) ? qhi : khi;
    _Float16* o2 = (zz == 0) ? qlo : klo;
    #pragma unroll
    for (int rs = 0; rs < 2; rs++) {
        #pragma unroll
        for (int tl = 0; tl < 4; tl++) {
            #pragma unroll
            for (int r = 0; r < 4; r++) {
                const int gr = bm + (w << 5) + (rs << 4) + (quad << 2) + r;
                const float val = acc[rs][tl][r];
                const int b = gr >> 11, n = gr & 2047;
                const int d = (tl << 4) + m16;
                const int bh = (b << 3) + by;
                if (zz == 2) {
                    const int kp = (((n >> 2) & 3) << 3) | (((n >> 4) & 1) << 2) | (n & 3);
                    vT[(((size_t)((bh << 6) + (n >> 5)) << 6) + d) * 32 + kp] = (_Float16)val;
                } else {
                    const size_t idx = ((((size_t)bh << 11) + n) << 6) + d;
                    const _Float16 hh = (_Float16)val;
                    o1[idx] = hh;
                    o2[idx] = (_Float16)(val - (float)hh);
                }
            }
        }
    }
}

// ---------------------------------------------------------------------------
// K2: MFMA split-f16 argmax. 64-key chunks, 4-tl, single-buffered LDS.
// Key-split x8 -> 2048 blocks = 8/CU (round 12 showed the GRID, not LDS,
// capped residency at 4 blocks/CU / 34% occupancy). 18 KB LDS x 8 = 144 KB,
// VGPR ~60 <= 64 -> full 32 waves/CU for latency hiding. Row argmax ->
// global atomicMax; col argmax -> in-lane, quad butterfly, LDS atomicMax.
// ---------------------------------------------------------------------------
__global__ __launch_bounds__(256) void argmax_mfma(
        const _Float16* __restrict__ qhi, const _Float16* __restrict__ qlo,
        const _Float16* __restrict__ khi, const _Float16* __restrict__ klo,
        unsigned long long* __restrict__ rowP, unsigned long long* __restrict__ colP)
{
    __shared__ __attribute__((aligned(16))) _Float16 Ksh[2][4096];     // 16 KB
    __shared__ unsigned long long colbest[256];                        // 2 KB
    const int bx = blockIdx.x;
    const int bh = ((bx & 7) << 1) | (bx >> 10);           // 2048 blocks
    const int mid = (bx >> 3) & 127;
    const int rt = mid & 15;
    const int ks = mid >> 4;                               // 0..7, 256 keys
    const int t = threadIdx.x, w = t >> 6, lane = t & 63;
    const int m16 = lane & 15, quad = lane >> 4;
    const int wrow = (rt << 7) + (w << 5);
    const size_t qoff0 = ((((size_t)bh << 11) + wrow + m16) << 6) + (quad << 3);
    const size_t qoff1 = qoff0 + 1024;
    const f16x8_t a00h = load_h8(qhi + qoff0), a01h = load_h8(qhi + qoff0 + 32);
    const f16x8_t a00l = load_h8(qlo + qoff0), a01l = load_h8(qlo + qoff0 + 32);
    const f16x8_t a10h = load_h8(qhi + qoff1), a11h = load_h8(qhi + qoff1 + 32);
    const f16x8_t a10l = load_h8(qlo + qoff1), a11l = load_h8(qlo + qoff1 + 32);
    for (int c = t; c < 256; c += 256) colbest[c] = 0;
    const int krow = lane >> 3, kblk = (lane & 7) ^ (krow & 7);
    const int e = m16 & 7;
    const int s00 = (quad ^ e) << 3, s01 = ((4 + quad) ^ e) << 3;
    const size_t kbase = (((size_t)bh << 11) + (ks << 8)) << 6;
    float bv0[4] = {-3.4e38f, -3.4e38f, -3.4e38f, -3.4e38f};
    float bv1[4] = {-3.4e38f, -3.4e38f, -3.4e38f, -3.4e38f};
    int bc0[4] = {0, 0, 0, 0}, bc1[4] = {0, 0, 0, 0};
    const f32x4_t z = {0.f, 0.f, 0.f, 0.f};

    auto stage = [&](int cidx) {
        const size_t ce = kbase + ((size_t)cidx << 12);
        #pragma unroll
        for (int ci = 0; ci < 4; ci++) {
            const int pp = (w << 2) + ci;
            const int s = pp >> 3, pj = pp & 7;
            const _Float16* src = (s ? klo : khi) + ce + (((pj << 3) + krow) << 6) + (kblk << 3);
            gload_lds16(src, &Ksh[s][pj << 9]);
        }
    };

    for (int ch = 0; ch < 4; ch++) {
        __syncthreads();                          // prior compute done
        stage(ch);
        asm volatile("s_waitcnt vmcnt(0)" ::: "memory");
        __syncthreads();                          // chunk staged for all waves
        const _Float16* K0 = Ksh[0];
        const _Float16* K1 = Ksh[1];
        const int kc0 = (ks << 8) + (ch << 6);
        #pragma unroll
        for (int tl = 0; tl < 4; tl++) {
            const int j64 = ((tl << 4) + m16) << 6;
            const f16x8_t bh0 = load_h8(&K0[j64 + s00]);
            const f16x8_t bh1 = load_h8(&K0[j64 + s01]);
            const f16x8_t bl0 = load_h8(&K1[j64 + s00]);
            const f16x8_t bl1 = load_h8(&K1[j64 + s01]);
            f32x4_t c0 = MFMAH(a00h, bh0, z);
            c0 = MFMAH(a01h, bh1, c0);
            c0 = MFMAH(a00l, bh0, c0); c0 = MFMAH(a01l, bh1, c0);
            c0 = MFMAH(a00h, bl0, c0); c0 = MFMAH(a01h, bl1, c0);
            f32x4_t c1 = MFMAH(a10h, bh0, z);
            c1 = MFMAH(a11h, bh1, c1);
            c1 = MFMAH(a10l, bh0, c1); c1 = MFMAH(a11l, bh1, c1);
            c1 = MFMAH(a10h, bl0, c1); c1 = MFMAH(a11h, bl1, c1);
            const int gc = kc0 + (tl << 4) + m16;
            #pragma unroll
            for (int r = 0; r < 4; r++) {
                if (c0[r] > bv0[r]) { bv0[r] = c0[r]; bc0[r] = gc; }
                if (c1[r] > bv1[r]) { bv1[r] = c1[r]; bc1[r] = gc; }
            }
            // col argmax: in-lane over 8 rows (rowset0 first -> smallest row)
            float v = c0[0]; int ri = (quad << 2);
            if (c0[1] > v) { v = c0[1]; ri = (quad << 2) + 1; }
            if (c0[2] > v) { v = c0[2]; ri = (quad << 2) + 2; }
            if (c0[3] > v) { v = c0[3]; ri = (quad << 2) + 3; }
            if (c1[0] > v) { v = c1[0]; ri = 16 + (quad << 2); }
            if (c1[1] > v) { v = c1[1]; ri = 16 + (quad << 2) + 1; }
            if (c1[2] > v) { v = c1[2]; ri = 16 + (quad << 2) + 2; }
            if (c1[3] > v) { v = c1[3]; ri = 16 + (quad << 2) + 3; }
            unsigned long long pk = packVR(v, wrow + ri);
            pk = max64(pk, shflx64(pk, 16));
            pk = max64(pk, shflx64(pk, 32));
            if (quad == 0) atomicMax(&colbest[(ch << 6) + (tl << 4) + m16], pk);
        }
    }
    #pragma unroll
    for (int r = 0; r < 4; r++) {
        unsigned long long p0 = packVR(bv0[r], bc0[r]);
        p0 = max64(p0, shflx64(p0, 1)); p0 = max64(p0, shflx64(p0, 2));
        p0 = max64(p0, shflx64(p0, 4)); p0 = max64(p0, shflx64(p0, 8));
        if (m16 == 0)
            atomicMax(rowP + ((size_t)bh << 11) + wrow + (quad << 2) + r, p0);
        unsigned long long p1 = packVR(bv1[r], bc1[r]);
        p1 = max64(p1, shflx64(p1, 1)); p1 = max64(p1, shflx64(p1, 2));
        p1 = max64(p1, shflx64(p1, 4)); p1 = max64(p1, shflx64(p1, 8));
        if (m16 == 0)
            atomicMax(rowP + ((size_t)bh << 11) + wrow + 16 + (quad << 2) + r, p1);
    }
    __syncthreads();
    for (int c = t; c < 256; c += 256)
        atomicMax(colP + ((size_t)bh << 11) + (ks << 8) + c, colbest[c]);
}

// ---------------------------------------------------------------------------
// K4: fused attention, swapped-QK^T form, resolve fused into vnL prologue.
// 32 rows/wave, key-split x4 -> 1024 blocks = 4/CU. 64-key chunks (8
// barriers), ring-2 LDS + prefetch depth 1 (stage(ch+1) after barrier into
// the opposite buffer, race-free; lands under chunk-ch's compute).
// [round-10 version: best measured]
// ---------------------------------------------------------------------------
__global__ __launch_bounds__(256, 4) void attn_pv(
        const _Float16* __restrict__ qh, const _Float16* __restrict__ kh,
        const _Float16* __restrict__ vT,
        const unsigned long long* __restrict__ q2kP,
        const unsigned long long* __restrict__ k2qP,
        const int* __restrict__ supp_mask,
        const float* __restrict__ supp_valid,
        float* __restrict__ xp, float* __restrict__ lp)
{
    __shared__ __attribute__((aligned(16))) _Float16 Ksh[2][4096];    // 16 KB
    __shared__ __attribute__((aligned(16))) _Float16 Vsh[2][4096];    // 16 KB
    __shared__ __attribute__((aligned(16))) float vnL[512];           // 2 KB
    const int bx = blockIdx.x;
    const int bh = ((bx & 7) << 1) | (bx >> 9);            // 1024 blocks
    const int mid = (bx >> 3) & 63;
    const int rt = mid & 15, ks = mid >> 4;                // ks 0..3, 512 keys
    const int t = threadIdx.x, w = t >> 6, lane = t & 63;
    const int m16 = lane & 15, quad = lane >> 4;
    const int rowbase = (rt << 7) + (w << 5);              // 32 rows/wave
    const size_t qoff = ((((size_t)bh << 11) + rowbase + m16) << 6) + (quad << 3);
    const f16x8_t a0 = load_h8(qh + qoff), a1 = load_h8(qh + qoff + 32);
    const f16x8_t a2 = load_h8(qh + qoff + 1024), a3 = load_h8(qh + qoff + 1056);
    // fused resolve: vn[j] = (asso ? supp_valid : 1) * NEG * LOG2E - MFIX
    {
        const int b = bh >> 3;
        for (int c = t; c < 512; c += 256) {
            const int j = (ks << 9) + c;
            const unsigned k2q = 0xFFFFFFFFu
                - (unsigned)(k2qP[(bh << 11) + j] & 0xFFFFFFFFull);
            const unsigned rm = 0xFFFFFFFFu
                - (unsigned)(q2kP[(bh << 11) + (int)k2q] & 0xFFFFFFFFull);
            const int asso = supp_mask[(b << 11) + j] == supp_mask[(b << 11) + (int)rm];
            const float valid = asso ? supp_valid[(b << 11) + j] : 1.0f;
            vnL[c] = fmaf(valid, NEG_ * LOG2E_, -MFIX_);
        }
    }
    const float KS = SCALE_ * LOG2E_;
    const int krow = lane >> 3, kblk = (lane & 7) ^ ((lane >> 3) & 7);
    const int vrow = lane >> 2, vblk = (lane & 3) ^ ((lane >> 3) & 3);
    const int e = m16 & 7;
    const int s00 = (quad ^ e) << 3, s01 = ((4 + quad) ^ e) << 3;
    const int vsw = (m16 >> 1) & 3;
    f16x8_t ones;
    #pragma unroll
    for (int i = 0; i < 8; i++) ones[i] = (_Float16)1.0f;
    const f32x4_t z = {0.f, 0.f, 0.f, 0.f};
    f32x4_t xacc0[4], xacc1[4];
    #pragma unroll
    for (int nt = 0; nt < 4; nt++) { xacc0[nt] = z; xacc1[nt] = z; }
    f32x4_t lacc0 = z, lacc1 = z;

    // staging: waves 0-1 stage K (wave w -> keys 32w..32w+31), waves 2-3
    // stage V (wave w-2 -> 32-key tile w-2); 4 gload_lds per thread per
    // 64-key chunk, contiguous 2048-half span each; src steps 4096/chunk.
    const size_t kbel = ((size_t)bh << 11) * HD_;
    const bool isK = (w < 2);
    const _Float16* src;
    _Float16* dstBase;
    if (isK) {
        src = kh + kbel + ((size_t)ks << 15) + (w << 11) + (krow << 6) + (kblk << 3);
        dstBase = &Ksh[0][w << 11];
    } else {
        src = vT + (((size_t)(bh << 6) + (ks << 4)) << 11)
                 + ((w - 2) << 11) + (vrow << 5) + (vblk << 3);
        dstBase = &Vsh[0][(w - 2) << 11];
    }
    auto stage = [&](int bufidx) {
        _Float16* d = dstBase + (bufidx << 12);
        gload_lds16(src, d);
        gload_lds16(src + 512, d + 512);
        gload_lds16(src + 1024, d + 1024);
        gload_lds16(src + 1536, d + 1536);
        src += 4096;
    };

    __syncthreads();            // vnL visible to all waves
    stage(0);
    for (int ch = 0; ch < 8; ch++) {
        // chunk ch's loads landed; barrier; prefetch ch+1 into other buffer
        asm volatile("s_waitcnt vmcnt(0)" ::: "memory");
        __builtin_amdgcn_sched_barrier(0);
        __builtin_amdgcn_s_barrier();
        __builtin_amdgcn_sched_barrier(0);
        if (ch + 1 < 8) stage((ch + 1) & 1);
        #pragma unroll
        for (int hf = 0; hf < 2; hf++) {
            const _Float16* K = &Ksh[ch & 1][hf << 11];
            const _Float16* V = &Vsh[ch & 1][hf << 11];
            // K fragments (A-operand): rows = keys of this half-chunk
            const f16x8_t b00 = load_h8(&K[(m16 << 6) + s00]);
            const f16x8_t b01 = load_h8(&K[(m16 << 6) + s01]);
            const f16x8_t b10 = load_h8(&K[((16 + m16) << 6) + s00]);
            const f16x8_t b11 = load_h8(&K[((16 + m16) << 6) + s01]);
            // swapped QK^T: D[key][query]; c0/c1 rowset0, c2/c3 rowset1
            f32x4_t c0 = MFMAH(b00, a0, z); c0 = MFMAH(b01, a1, c0);
            f32x4_t c1 = MFMAH(b10, a0, z); c1 = MFMAH(b11, a1, c1);
            f32x4_t c2 = MFMAH(b00, a2, z); c2 = MFMAH(b01, a3, c2);
            f32x4_t c3 = MFMAH(b10, a2, z); c3 = MFMAH(b11, a3, c3);
            const int vb = (ch << 6) + (hf << 5);
            const f32x4_t vn0 = *reinterpret_cast<const f32x4_t*>(&vnL[vb + (quad << 2)]);
            const f32x4_t vn1 = *reinterpret_cast<const f32x4_t*>(&vnL[vb + 16 + (quad << 2)]);
            union { h16x2_t h2[4]; f16x8_t v8; } pk0, pk1;
            pk0.h2[0] = __builtin_amdgcn_cvt_pkrtz(
                __builtin_amdgcn_exp2f(fmaf(c0[0], KS, vn0[0])),
                __builtin_amdgcn_exp2f(fmaf(c0[1], KS, vn0[1])));
            pk0.h2[1] = __builtin_amdgcn_cvt_pkrtz(
                __builtin_amdgcn_exp2f(fmaf(c0[2], KS, vn0[2])),
                __builtin_amdgcn_exp2f(fmaf(c0[3], KS, vn0[3])));
            pk0.h2[2] = __builtin_amdgcn_cvt_pkrtz(
                __builtin_amdgcn_exp2f(fmaf(c1[0], KS, vn1[0])),
                __builtin_amdgcn_exp2f(fmaf(c1[1], KS, vn1[1])));
            pk0.h2[3] = __builtin_amdgcn_cvt_pkrtz(
                __builtin_amdgcn_exp2f(fmaf(c1[2], KS, vn1[2])),
                __builtin_amdgcn_exp2f(fmaf(c1[3], KS, vn1[3])));
            pk1.h2[0] = __builtin_amdgcn_cvt_pkrtz(
                __builtin_amdgcn_exp2f(fmaf(c2[0], KS, vn0[0])),
                __builtin_amdgcn_exp2f(fmaf(c2[1], KS, vn0[1])));
            pk1.h2[1] = __builtin_amdgcn_cvt_pkrtz(
                __builtin_amdgcn_exp2f(fmaf(c2[2], KS, vn0[2])),
                __builtin_amdgcn_exp2f(fmaf(c2[3], KS, vn0[3])));
            pk1.h2[2] = __builtin_amdgcn_cvt_pkrtz(
                __builtin_amdgcn_exp2f(fmaf(c3[0], KS, vn1[0])),
                __builtin_amdgcn_exp2f(fmaf(c3[1], KS, vn1[1])));
            pk1.h2[3] = __builtin_amdgcn_cvt_pkrtz(
                __builtin_amdgcn_exp2f(fmaf(c3[2], KS, vn1[2])),
                __builtin_amdgcn_exp2f(fmaf(c3[3], KS, vn1[3])));
            const f16x8_t pa0 = pk0.v8, pa1 = pk1.v8;
            lacc0 = MFMAH(pa0, ones, lacc0);
            lacc1 = MFMAH(pa1, ones, lacc1);
            #pragma unroll
            for (int nt = 0; nt < 4; nt++) {
                const f16x8_t vb2 = load_h8(&V[((nt * 16 + m16) << 5) + ((quad ^ vsw) << 3)]);
                xacc0[nt] = MFMAH(pa0, vb2, xacc0[nt]);
                xacc1[nt] = MFMAH(pa1, vb2, xacc1[nt]);
            }
        }
    }
    const int b = bh >> 3, h = bh & 7;
    if (m16 == 0) {
        #pragma unroll
        for (int r = 0; r < 4; r++) {
            lp[((size_t)ks << 15) + (bh << 11) + rowbase + (quad << 2) + r] = lacc0[r];
            lp[((size_t)ks << 15) + (bh << 11) + rowbase + 16 + (quad << 2) + r] = lacc1[r];
        }
    }
    const size_t xbase = ((size_t)ks << 21);
    #pragma unroll
    for (int r = 0; r < 4; r++) {
        const int row0 = rowbase + (quad << 2) + r;
        const int row1 = row0 + 16;
        #pragma unroll
        for (int nt = 0; nt < 4; nt++) {
            xp[xbase + (((size_t)(b << 11) + row0) << 9) + (h << 6) + (nt << 4) + m16] = xacc0[nt][r];
            xp[xbase + (((size_t)(b << 11) + row1) << 9) + (h << 6) + (nt << 4) + m16] = xacc1[nt][r];
        }
    }
}

// ---------------------------------------------------------------------------
// K4b: combine4 -- A = (xp0+xp1+xp2+xp3) * 1/(l0+l1+l2+l3), f16 hi/lo split,
// flat [4096][512]. Fully parallel, vectorized; takes the combine off
// out_gemm's latency-critical path.
// ---------------------------------------------------------------------------
__global__ __launch_bounds__(256) void combine4(
        const float* __restrict__ xp, const float* __restrict__ lp,
        _Float16* __restrict__ Ahi, _Float16* __restrict__ Alo)
{
    const int gid = blockIdx.x * 256 + threadIdx.x;    // 262144 = 4096*512/8
    const int r = gid >> 6, c8 = gid & 63;             // row, col-block of 8
    const int b = r >> 11, n = r & 2047, h = c8 >> 3;  // head = (c8*8)>>6
    const size_t li = ((size_t)((b << 3) + h) << 11) + n;
    const float linv = 1.0f / (lp[li] + lp[32768 + li] + lp[65536 + li] + lp[98304 + li]);
    const size_t o = (size_t)gid << 3;                 // f32 index into [4096][512]
    const float4* x0 = reinterpret_cast<const float4*>(xp + o);
    const float4* x1 = reinterpret_cast<const float4*>(xp + 2097152 + o);
    const float4* x2 = reinterpret_cast<const float4*>(xp + 4194304 + o);
    const float4* x3 = reinterpret_cast<const float4*>(xp + 6291456 + o);
    f16x8_t hv, lv;
    #pragma unroll
    for (int s = 0; s < 2; s++) {
        const float4 p0 = x0[s], p1 = x1[s], p2 = x2[s], p3 = x3[s];
        float vv[4];
        vv[0] = (p0.x + p1.x + p2.x + p3.x) * linv;
        vv[1] = (p0.y + p1.y + p2.y + p3.y) * linv;
        vv[2] = (p0.z + p1.z + p2.z + p3.z) * linv;
        vv[3] = (p0.w + p1.w + p2.w + p3.w) * linv;
        #pragma unroll
        for (int i = 0; i < 4; i++) {
            const _Float16 hh = (_Float16)vv[i];
            hv[s * 4 + i] = hh;
            lv[s * 4 + i] = (_Float16)(vv[i] - (float)hh);
        }
    }
    *reinterpret_cast<f16x8_t*>(Ahi + o) = hv;
    *reinterpret_cast<f16x8_t*>(Alo + o) = lv;
}

// ---------------------------------------------------------------------------
// K5: output GEMM. A read pre-combined/pre-split from Ahi/Alo (f16), pure
// vector loads; out[m,j] = sum_k A[m,k]*Wproj[j,k], fp32 out.
// ---------------------------------------------------------------------------
__global__ __launch_bounds__(256) void out_gemm(
        const _Float16* __restrict__ Ahi, const _Float16* __restrict__ Alo,
        const _Float16* __restrict__ Wh, const _Float16* __restrict__ Wl,
        float* __restrict__ outF)
{
    __shared__ __attribute__((aligned(16))) _Float16 Wsh[2][2][4096];  // 32 KB
    const int t = threadIdx.x, w = t >> 6, lane = t & 63;
    const int m16 = lane & 15, quad = lane >> 4;
    const int bm = blockIdx.x << 7, bn = blockIdx.y << 6;
    const int r0 = bm + (w << 5) + m16, r1 = r0 + 16;
    const int krow = lane >> 3, kblk = (lane & 7) ^ (krow & 7);
    const int e = m16 & 7;
    const int s00 = (quad ^ e) << 3, s01 = ((4 + quad) ^ e) << 3;
    const f32x4_t z = {0.f, 0.f, 0.f, 0.f};
    f32x4_t acc[2][4];
    #pragma unroll
    for (int rs = 0; rs < 2; rs++)
        #pragma unroll
        for (int tl = 0; tl < 4; tl++) acc[rs][tl] = z;

    auto stageW = [&](int buf, int kc) {
        #pragma unroll
        for (int ci = 0; ci < 4; ci++) {
            const int pp = (w << 2) + ci;
            const int s = pp >> 3, pj = pp & 7;
            const _Float16* src = (s ? Wl : Wh)
                + (size_t)(bn + (pj << 3) + krow) * C_ + kc + (kblk << 3);
            gload_lds16(src, &Wsh[buf][s][pj << 9]);
        }
    };
    auto loadA = [&](int ch, f16x8_t* d) {
        const int kc = ch << 6;                       // head = ch
        #pragma unroll
        for (int rs = 0; rs < 2; rs++) {
            const size_t base = ((size_t)(rs ? r1 : r0) << 9) + kc + (quad << 3);
            d[rs * 4 + 0] = load_h8(Ahi + base);
            d[rs * 4 + 1] = load_h8(Ahi + base + 32);
            d[rs * 4 + 2] = load_h8(Alo + base);
            d[rs * 4 + 3] = load_h8(Alo + base + 32);
        }
    };

    f16x8_t cA[8], nA[8];
    stageW(0, 0);
    loadA(0, cA);
    for (int ch = 0; ch < 8; ch++) {
        __syncthreads();
        if (ch + 1 < 8) {
            stageW((ch + 1) & 1, (ch + 1) << 6);
            loadA(ch + 1, nA);
        }
        const _Float16* W0 = Wsh[ch & 1][0];
        const _Float16* W1 = Wsh[ch & 1][1];
        #pragma unroll
        for (int tl = 0; tl < 4; tl++) {
            const int j64 = ((tl << 4) + m16) << 6;
            const f16x8_t bh0 = load_h8(&W0[j64 + s00]);
            const f16x8_t bh1 = load_h8(&W0[j64 + s01]);
            const f16x8_t bl0 = load_h8(&W1[j64 + s00]);
            const f16x8_t bl1 = load_h8(&W1[j64 + s01]);
            f32x4_t c0 = acc[0][tl];
            c0 = MFMAH(cA[0], bh0, c0); c0 = MFMAH(cA[1], bh1, c0);
            c0 = MFMAH(cA[2], bh0, c0); c0 = MFMAH(cA[3], bh1, c0);
            c0 = MFMAH(cA[0], bl0, c0); c0 = MFMAH(cA[1], bl1, c0);
            acc[0][tl] = c0;
            f32x4_t c1 = acc[1][tl];
            c1 = MFMAH(cA[4], bh0, c1); c1 = MFMAH(cA[5], bh1, c1);
            c1 = MFMAH(cA[6], bh0, c1); c1 = MFMAH(cA[7], bh1, c1);
            c1 = MFMAH(cA[4], bl0, c1); c1 = MFMAH(cA[5], bl1, c1);
            acc[1][tl] = c1;
        }
        #pragma unroll
        for (int i = 0; i < 8; i++) cA[i] = nA[i];
    }
    #pragma unroll
    for (int rs = 0; rs < 2; rs++) {
        #pragma unroll
        for (int tl = 0; tl < 4; tl++) {
            #pragma unroll
            for (int r = 0; r < 4; r++) {
                const int gr = bm + (w << 5) + (rs << 4) + (quad << 2) + r;
                const int gj = bn + (tl << 4) + m16;
                outF[(size_t)gr * C_ + gj] = acc[rs][tl][r];
            }
        }
    }
}

// ---------------------------------------------------------------------------
extern "C" void kernel_launch(void* const* d_in, const int* in_sizes, int n_in,
                              void* d_out, int out_size, void* d_ws, size_t ws_size,
                              hipStream_t stream) {
    const float* q  = (const float*)d_in[0];
    const float* k  = (const float*)d_in[1];
    const float* v  = (const float*)d_in[2];
    const float* supp_valid = (const float*)d_in[3];
    const int*   supp_mask  = (const int*)d_in[4];
    const float* Wq = (const float*)d_in[5];
    const float* Wk = (const float*)d_in[6];
    const float* Wv = (const float*)d_in[7];
    const float* Wp = (const float*)d_in[8];
    float* out = (float*)d_out;

    char* p = (char*)d_ws;
    _Float16* qhi = (_Float16*)p;      p += 4194304;   // [bh][n][d] f16 splits
    _Float16* qlo = (_Float16*)p;      p += 4194304;
    _Float16* khi = (_Float16*)p;      p += 4194304;
    _Float16* klo = (_Float16*)p;      p += 4194304;
    _Float16* vT  = (_Float16*)p;      p += 4194304;   // [bh] chunk-tiled (k')
    float* xp     = (float*)p;         p += 33554432;  // [4][4096][512] f32
    _Float16* wH  = (_Float16*)p;      p += 2097152;   // [4][512*512]
    _Float16* wL  = (_Float16*)p;      p += 2097152;
    _Float16* Ahi = (_Float16*)p;      p += 4194304;   // [4096][512] f16
    _Float16* Alo = (_Float16*)p;      p += 4194304;
    unsigned long long* q2kP = (unsigned long long*)p; p += 262144;
    unsigned long long* k2qP = (unsigned long long*)p; p += 262144;
    float* lp = (float*)p;             p += 524288;    // [4][16][2048]

    (void)hipMemsetAsync(q2kP, 0, 524288, stream);     // rowP + colP zero init

    dim3 bG(256);
    wsplit4<<<dim3(256, 4), bG, 0, stream>>>(Wq, Wk, Wv, Wp, wH, wL);
    proj_gemm<<<dim3(32, 8, 3), bG, 0, stream>>>(q, k, v, wH, wL,
                                                 qhi, qlo, khi, klo, vT);

    argmax_mfma<<<2048, bG, 0, stream>>>(qhi, qlo, khi, klo, q2kP, k2qP);

    attn_pv<<<1024, bG, 0, stream>>>(qhi, khi, vT, q2kP, k2qP,
                                     supp_mask, supp_valid, xp, lp);

    combine4<<<1024, bG, 0, stream>>>(xp, lp, Ahi, Alo);

    out_gemm<<<dim3(32, 8), bG, 0, stream>>>(Ahi, Alo,
                                             wH + 3 * 262144, wL + 3 * 262144, out);
}

// Round 14
// 206.433 us; speedup vs baseline: 1.0137x; 1.0137x over previous
//
#include <hip/hip_runtime.h>
#include <hip/hip_bf16.h>
#include <stdint.h>

#define H_ 8
#define NS_ 2048
#define C_ 512
#define HD_ 64
#define SCALE_ 0.125f
#define NEG_ -10000.0f
#define LOG2E_ 1.4426950408889634f
#define MFIX_ 4.0f

typedef _Float16 f16x8_t __attribute__((ext_vector_type(8)));
typedef _Float16 f16x4_t __attribute__((ext_vector_type(4)));
typedef __fp16 h16x2_t __attribute__((ext_vector_type(2)));   // cvt_pkrtz ret type
typedef float f32x4_t __attribute__((ext_vector_type(4)));

#define MFMAH(a, b, c) __builtin_amdgcn_mfma_f32_16x16x32_f16(a, b, c, 0, 0, 0)

__device__ inline f16x8_t load_h8(const _Float16* p) {
    return *reinterpret_cast<const f16x8_t*>(p);
}

// async global->LDS, 16B per lane; LDS dest = uniform base + lane*16
__device__ inline void gload_lds16(const void* g, void* l) {
    __builtin_amdgcn_global_load_lds(
        (const __attribute__((address_space(1))) unsigned int*)g,
        (__attribute__((address_space(3))) unsigned int*)l, 16, 0, 0);
}

__device__ inline unsigned orderF(float v) {
    unsigned u = __float_as_uint(v);
    return (u & 0x80000000u) ? ~u : (u | 0x80000000u);
}
__device__ inline unsigned long long packVR(float v, int idx) {
    return ((unsigned long long)orderF(v) << 32) | (unsigned)(~idx);
}
__device__ inline unsigned long long max64(unsigned long long a, unsigned long long b) {
    return a > b ? a : b;
}
__device__ inline unsigned long long shflx64(unsigned long long x, int m) {
    unsigned lo = (unsigned)x, hi = (unsigned)(x >> 32);
    lo = __shfl_xor(lo, m, 64);
    hi = __shfl_xor(hi, m, 64);
    return ((unsigned long long)hi << 32) | lo;
}

// ---------------------------------------------------------------------------
// K0: all four 512x512 weights -> f16 hi/lo splits in one launch.
// ---------------------------------------------------------------------------
__global__ __launch_bounds__(256) void wsplit4(
        const float* __restrict__ w0, const float* __restrict__ w1,
        const float* __restrict__ w2, const float* __restrict__ w3,
        _Float16* __restrict__ hi, _Float16* __restrict__ lo)
{
    const int i = blockIdx.x * 256 + threadIdx.x;            // 65536 float4 / W
    const int y = blockIdx.y;
    const float* src = (y == 0) ? w0 : (y == 1) ? w1 : (y == 2) ? w2 : w3;
    const float4 v = reinterpret_cast<const float4*>(src)[i];
    f16x4_t hv, lv;
    hv[0] = (_Float16)v.x; hv[1] = (_Float16)v.y;
    hv[2] = (_Float16)v.z; hv[3] = (_Float16)v.w;
    lv[0] = (_Float16)(v.x - (float)hv[0]);
    lv[1] = (_Float16)(v.y - (float)hv[1]);
    lv[2] = (_Float16)(v.z - (float)hv[2]);
    lv[3] = (_Float16)(v.w - (float)hv[3]);
    const size_t o = ((size_t)y << 16) + i;                  // float4 index
    reinterpret_cast<f16x4_t*>(hi)[o] = hv;
    reinterpret_cast<f16x4_t*>(lo)[o] = lv;
}

// ---------------------------------------------------------------------------
// K1: projection GEMM (q/k/v via grid.z). 3-term split-f16 MFMA (~fp32).
// z<2: hi/lo split out [bh][n][d]; z==2: V tiled [bh][key>>5][d][k'] with
// k' = ((key>>2)&3)<<3 | ((key>>4)&1)<<2 | (key&3)
// (chosen so attn_pv's in-register P fragment k-slot quad*8+i hits its keys).
// ---------------------------------------------------------------------------
__global__ __launch_bounds__(256) void proj_gemm(
        const float* __restrict__ qin, const float* __restrict__ kin,
        const float* __restrict__ vin,
        const _Float16* __restrict__ wHall, const _Float16* __restrict__ wLall,
        _Float16* __restrict__ qhi, _Float16* __restrict__ qlo,
        _Float16* __restrict__ khi, _Float16* __restrict__ klo,
        _Float16* __restrict__ vT)
{
    __shared__ __attribute__((aligned(16))) _Float16 Wsh[2][2][4096];  // 32 KB
    const int zz = blockIdx.z;
    const float* A32 = (zz == 0) ? qin : (zz == 1) ? kin : vin;
    const _Float16* Wh = wHall + ((size_t)zz << 18);
    const _Float16* Wl = wLall + ((size_t)zz << 18);
    const int t = threadIdx.x, w = t >> 6, lane = t & 63;
    const int m16 = lane & 15, quad = lane >> 4;
    const int bm = blockIdx.x << 7, bn = blockIdx.y << 6;
    const int r0 = bm + (w << 5) + m16, r1 = r0 + 16;
    const int krow = lane >> 3, kblk = (lane & 7) ^ (krow & 7);
    const int e = m16 & 7;
    const int s00 = (quad ^ e) << 3, s01 = ((4 + quad) ^ e) << 3;
    const f32x4_t z = {0.f, 0.f, 0.f, 0.f};
    f32x4_t acc[2][4];
    #pragma unroll
    for (int rs = 0; rs < 2; rs++)
        #pragma unroll
        for (int tl = 0; tl < 4; tl++) acc[rs][tl] = z;

    auto stageW = [&](int buf, int kc) {
        #pragma unroll
        for (int ci = 0; ci < 4; ci++) {
            const int pp = (w << 2) + ci;
            const int s = pp >> 3, pj = pp & 7;
            const _Float16* src = (s ? Wl : Wh)
                + (size_t)(bn + (pj << 3) + krow) * C_ + kc + (kblk << 3);
            gload_lds16(src, &Wsh[buf][s][pj << 9]);
        }
    };
    auto loadA = [&](int kc, f16x8_t* d) {
        #pragma unroll
        for (int rs = 0; rs < 2; rs++) {
            const float* pr = A32 + (size_t)(rs ? r1 : r0) * C_ + kc + (quad << 3);
            #pragma unroll
            for (int seg = 0; seg < 2; seg++) {
                f16x8_t hv, lv;
                #pragma unroll
                for (int i = 0; i < 8; i++) {
                    const float x = pr[seg * 32 + i];
                    const _Float16 hh = (_Float16)x;
                    hv[i] = hh;
                    lv[i] = (_Float16)(x - (float)hh);
                }
                d[rs * 4 + seg] = hv;
                d[rs * 4 + seg + 2] = lv;
            }
        }
    };

    f16x8_t cA[8], nA[8];
    stageW(0, 0);
    loadA(0, cA);
    for (int ch = 0; ch < 8; ch++) {
        __syncthreads();
        if (ch + 1 < 8) {
            stageW((ch + 1) & 1, (ch + 1) << 6);
            loadA((ch + 1) << 6, nA);
        }
        const _Float16* W0 = Wsh[ch & 1][0];
        const _Float16* W1 = Wsh[ch & 1][1];
        #pragma unroll
        for (int tl = 0; tl < 4; tl++) {
            const int j64 = ((tl << 4) + m16) << 6;
            const f16x8_t bh0 = load_h8(&W0[j64 + s00]);
            const f16x8_t bh1 = load_h8(&W0[j64 + s01]);
            const f16x8_t bl0 = load_h8(&W1[j64 + s00]);
            const f16x8_t bl1 = load_h8(&W1[j64 + s01]);
            f32x4_t c0 = acc[0][tl];
            c0 = MFMAH(cA[0], bh0, c0); c0 = MFMAH(cA[1], bh1, c0);
            c0 = MFMAH(cA[2], bh0, c0); c0 = MFMAH(cA[3], bh1, c0);
            c0 = MFMAH(cA[0], bl0, c0); c0 = MFMAH(cA[1], bl1, c0);
            acc[0][tl] = c0;
            f32x4_t c1 = acc[1][tl];
            c1 = MFMAH(cA[4], bh0, c1); c1 = MFMAH(cA[5], bh1, c1);
            c1 = MFMAH(cA[6], bh0, c1); c1 = MFMAH(cA[7], bh1, c1);
            c1 = MFMAH(cA[4], bl0, c1); c1 = MFMAH(cA[5], bl1, c1);
            acc[1][tl] = c1;
        }
        #pragma unroll
        for (int i = 0; i < 8; i++) cA[i] = nA[i];
    }
    const int by = blockIdx.y;
    _Float16* o1 = (zz == 0) ? qhi : khi;
    _Float16* o2 = (zz == 0) ? qlo : klo;
    #pragma unroll
    for (int rs = 0; rs < 2; rs++) {
        #pragma unroll
        for (int tl = 0; tl < 4; tl++) {
            #pragma unroll
            for (int r = 0; r < 4; r++) {
                const int gr = bm + (w << 5) + (rs << 4) + (quad << 2) + r;
                const float val = acc[rs][tl][r];
                const int b = gr >> 11, n = gr & 2047;
                const int d = (tl << 4) + m16;
                const int bh = (b << 3) + by;
                if (zz == 2) {
                    const int kp = (((n >> 2) & 3) << 3) | (((n >> 4) & 1) << 2) | (n & 3);
                    vT[(((size_t)((bh << 6) + (n >> 5)) << 6) + d) * 32 + kp] = (_Float16)val;
                } else {
                    const size_t idx = ((((size_t)bh << 11) + n) << 6) + d;
                    const _Float16 hh = (_Float16)val;
                    o1[idx] = hh;
                    o2[idx] = (_Float16)(val - (float)hh);
                }
            }
        }
    }
}

// ---------------------------------------------------------------------------
// K2: MFMA split-f16 argmax. 64-key chunks, 4-tl, single-buffered LDS
// (20.5 KB), key-split x4 -> 1024 blocks. [round-10 form: best measured;
// ks x8 (round 13) doubled staging/atomic overhead for no occupancy gain]
// Row argmax -> global atomicMax; col argmax -> in-lane reduce, quad
// butterfly, LDS atomicMax, block merge.
// ---------------------------------------------------------------------------
__global__ __launch_bounds__(256) void argmax_mfma(
        const _Float16* __restrict__ qhi, const _Float16* __restrict__ qlo,
        const _Float16* __restrict__ khi, const _Float16* __restrict__ klo,
        unsigned long long* __restrict__ rowP, unsigned long long* __restrict__ colP)
{
    __shared__ __attribute__((aligned(16))) _Float16 Ksh[2][4096];     // 16 KB
    __shared__ unsigned long long colbest[512];                        // 4 KB
    const int bx = blockIdx.x;
    const int bh = ((bx & 7) << 1) | (bx >> 9);            // 1024 blocks
    const int mid = (bx >> 3) & 63;
    const int rt = mid & 15;
    const int ks = mid >> 4;                               // 0..3, 512 keys
    const int t = threadIdx.x, w = t >> 6, lane = t & 63;
    const int m16 = lane & 15, quad = lane >> 4;
    const int wrow = (rt << 7) + (w << 5);
    const size_t qoff0 = ((((size_t)bh << 11) + wrow + m16) << 6) + (quad << 3);
    const size_t qoff1 = qoff0 + 1024;
    const f16x8_t a00h = load_h8(qhi + qoff0), a01h = load_h8(qhi + qoff0 + 32);
    const f16x8_t a00l = load_h8(qlo + qoff0), a01l = load_h8(qlo + qoff0 + 32);
    const f16x8_t a10h = load_h8(qhi + qoff1), a11h = load_h8(qhi + qoff1 + 32);
    const f16x8_t a10l = load_h8(qlo + qoff1), a11l = load_h8(qlo + qoff1 + 32);
    for (int c = t; c < 512; c += 256) colbest[c] = 0;
    const int krow = lane >> 3, kblk = (lane & 7) ^ (krow & 7);
    const int e = m16 & 7;
    const int s00 = (quad ^ e) << 3, s01 = ((4 + quad) ^ e) << 3;
    const size_t kbase = (((size_t)bh << 11) + (ks << 9)) << 6;
    float bv0[4] = {-3.4e38f, -3.4e38f, -3.4e38f, -3.4e38f};
    float bv1[4] = {-3.4e38f, -3.4e38f, -3.4e38f, -3.4e38f};
    int bc0[4] = {0, 0, 0, 0}, bc1[4] = {0, 0, 0, 0};
    const f32x4_t z = {0.f, 0.f, 0.f, 0.f};

    auto stage = [&](int cidx) {
        const size_t ce = kbase + ((size_t)cidx << 12);
        #pragma unroll
        for (int ci = 0; ci < 4; ci++) {
            const int pp = (w << 2) + ci;
            const int s = pp >> 3, pj = pp & 7;
            const _Float16* src = (s ? klo : khi) + ce + (((pj << 3) + krow) << 6) + (kblk << 3);
            gload_lds16(src, &Ksh[s][pj << 9]);
        }
    };

    for (int ch = 0; ch < 8; ch++) {
        __syncthreads();                          // prior compute done
        stage(ch);
        asm volatile("s_waitcnt vmcnt(0)" ::: "memory");
        __syncthreads();                          // chunk staged for all waves
        const _Float16* K0 = Ksh[0];
        const _Float16* K1 = Ksh[1];
        const int kc0 = (ks << 9) + (ch << 6);
        #pragma unroll
        for (int tl = 0; tl < 4; tl++) {
            const int j64 = ((tl << 4) + m16) << 6;
            const f16x8_t bh0 = load_h8(&K0[j64 + s00]);
            const f16x8_t bh1 = load_h8(&K0[j64 + s01]);
            const f16x8_t bl0 = load_h8(&K1[j64 + s00]);
            const f16x8_t bl1 = load_h8(&K1[j64 + s01]);
            f32x4_t c0 = MFMAH(a00h, bh0, z);
            c0 = MFMAH(a01h, bh1, c0);
            c0 = MFMAH(a00l, bh0, c0); c0 = MFMAH(a01l, bh1, c0);
            c0 = MFMAH(a00h, bl0, c0); c0 = MFMAH(a01h, bl1, c0);
            f32x4_t c1 = MFMAH(a10h, bh0, z);
            c1 = MFMAH(a11h, bh1, c1);
            c1 = MFMAH(a10l, bh0, c1); c1 = MFMAH(a11l, bh1, c1);
            c1 = MFMAH(a10h, bl0, c1); c1 = MFMAH(a11h, bl1, c1);
            const int gc = kc0 + (tl << 4) + m16;
            #pragma unroll
            for (int r = 0; r < 4; r++) {
                if (c0[r] > bv0[r]) { bv0[r] = c0[r]; bc0[r] = gc; }
                if (c1[r] > bv1[r]) { bv1[r] = c1[r]; bc1[r] = gc; }
            }
            // col argmax: in-lane over 8 rows (rowset0 first -> smallest row)
            float v = c0[0]; int ri = (quad << 2);
            if (c0[1] > v) { v = c0[1]; ri = (quad << 2) + 1; }
            if (c0[2] > v) { v = c0[2]; ri = (quad << 2) + 2; }
            if (c0[3] > v) { v = c0[3]; ri = (quad << 2) + 3; }
            if (c1[0] > v) { v = c1[0]; ri = 16 + (quad << 2); }
            if (c1[1] > v) { v = c1[1]; ri = 16 + (quad << 2) + 1; }
            if (c1[2] > v) { v = c1[2]; ri = 16 + (quad << 2) + 2; }
            if (c1[3] > v) { v = c1[3]; ri = 16 + (quad << 2) + 3; }
            unsigned long long pk = packVR(v, wrow + ri);
            pk = max64(pk, shflx64(pk, 16));
            pk = max64(pk, shflx64(pk, 32));
            if (quad == 0) atomicMax(&colbest[(ch << 6) + (tl << 4) + m16], pk);
        }
    }
    #pragma unroll
    for (int r = 0; r < 4; r++) {
        unsigned long long p0 = packVR(bv0[r], bc0[r]);
        p0 = max64(p0, shflx64(p0, 1)); p0 = max64(p0, shflx64(p0, 2));
        p0 = max64(p0, shflx64(p0, 4)); p0 = max64(p0, shflx64(p0, 8));
        if (m16 == 0)
            atomicMax(rowP + ((size_t)bh << 11) + wrow + (quad << 2) + r, p0);
        unsigned long long p1 = packVR(bv1[r], bc1[r]);
        p1 = max64(p1, shflx64(p1, 1)); p1 = max64(p1, shflx64(p1, 2));
        p1 = max64(p1, shflx64(p1, 4)); p1 = max64(p1, shflx64(p1, 8));
        if (m16 == 0)
            atomicMax(rowP + ((size_t)bh << 11) + wrow + 16 + (quad << 2) + r, p1);
    }
    __syncthreads();
    for (int c = t; c < 512; c += 256)
        atomicMax(colP + ((size_t)bh << 11) + (ks << 9) + c, colbest[c]);
}

// ---------------------------------------------------------------------------
// K4: fused attention, swapped-QK^T form, resolve fused into vnL prologue.
// 32 rows/wave, key-split x4 -> 1024 blocks = 4/CU. 64-key chunks (8
// barriers), ring-2 LDS + prefetch depth 1 (stage(ch+1) after barrier into
// the opposite buffer, race-free; lands under chunk-ch's compute).
// [round-10 version: best measured]
// ---------------------------------------------------------------------------
__global__ __launch_bounds__(256, 4) void attn_pv(
        const _Float16* __restrict__ qh, const _Float16* __restrict__ kh,
        const _Float16* __restrict__ vT,
        const unsigned long long* __restrict__ q2kP,
        const unsigned long long* __restrict__ k2qP,
        const int* __restrict__ supp_mask,
        const float* __restrict__ supp_valid,
        float* __restrict__ xp, float* __restrict__ lp)
{
    __shared__ __attribute__((aligned(16))) _Float16 Ksh[2][4096];    // 16 KB
    __shared__ __attribute__((aligned(16))) _Float16 Vsh[2][4096];    // 16 KB
    __shared__ __attribute__((aligned(16))) float vnL[512];           // 2 KB
    const int bx = blockIdx.x;
    const int bh = ((bx & 7) << 1) | (bx >> 9);            // 1024 blocks
    const int mid = (bx >> 3) & 63;
    const int rt = mid & 15, ks = mid >> 4;                // ks 0..3, 512 keys
    const int t = threadIdx.x, w = t >> 6, lane = t & 63;
    const int m16 = lane & 15, quad = lane >> 4;
    const int rowbase = (rt << 7) + (w << 5);              // 32 rows/wave
    const size_t qoff = ((((size_t)bh << 11) + rowbase + m16) << 6) + (quad << 3);
    const f16x8_t a0 = load_h8(qh + qoff), a1 = load_h8(qh + qoff + 32);
    const f16x8_t a2 = load_h8(qh + qoff + 1024), a3 = load_h8(qh + qoff + 1056);
    // fused resolve: vn[j] = (asso ? supp_valid : 1) * NEG * LOG2E - MFIX
    {
        const int b = bh >> 3;
        for (int c = t; c < 512; c += 256) {
            const int j = (ks << 9) + c;
            const unsigned k2q = 0xFFFFFFFFu
                - (unsigned)(k2qP[(bh << 11) + j] & 0xFFFFFFFFull);
            const unsigned rm = 0xFFFFFFFFu
                - (unsigned)(q2kP[(bh << 11) + (int)k2q] & 0xFFFFFFFFull);
            const int asso = supp_mask[(b << 11) + j] == supp_mask[(b << 11) + (int)rm];
            const float valid = asso ? supp_valid[(b << 11) + j] : 1.0f;
            vnL[c] = fmaf(valid, NEG_ * LOG2E_, -MFIX_);
        }
    }
    const float KS = SCALE_ * LOG2E_;
    const int krow = lane >> 3, kblk = (lane & 7) ^ ((lane >> 3) & 7);
    const int vrow = lane >> 2, vblk = (lane & 3) ^ ((lane >> 3) & 3);
    const int e = m16 & 7;
    const int s00 = (quad ^ e) << 3, s01 = ((4 + quad) ^ e) << 3;
    const int vsw = (m16 >> 1) & 3;
    f16x8_t ones;
    #pragma unroll
    for (int i = 0; i < 8; i++) ones[i] = (_Float16)1.0f;
    const f32x4_t z = {0.f, 0.f, 0.f, 0.f};
    f32x4_t xacc0[4], xacc1[4];
    #pragma unroll
    for (int nt = 0; nt < 4; nt++) { xacc0[nt] = z; xacc1[nt] = z; }
    f32x4_t lacc0 = z, lacc1 = z;

    // staging: waves 0-1 stage K (wave w -> keys 32w..32w+31), waves 2-3
    // stage V (wave w-2 -> 32-key tile w-2); 4 gload_lds per thread per
    // 64-key chunk, contiguous 2048-half span each; src steps 4096/chunk.
    const size_t kbel = ((size_t)bh << 11) * HD_;
    const bool isK = (w < 2);
    const _Float16* src;
    _Float16* dstBase;
    if (isK) {
        src = kh + kbel + ((size_t)ks << 15) + (w << 11) + (krow << 6) + (kblk << 3);
        dstBase = &Ksh[0][w << 11];
    } else {
        src = vT + (((size_t)(bh << 6) + (ks << 4)) << 11)
                 + ((w - 2) << 11) + (vrow << 5) + (vblk << 3);
        dstBase = &Vsh[0][(w - 2) << 11];
    }
    auto stage = [&](int bufidx) {
        _Float16* d = dstBase + (bufidx << 12);
        gload_lds16(src, d);
        gload_lds16(src + 512, d + 512);
        gload_lds16(src + 1024, d + 1024);
        gload_lds16(src + 1536, d + 1536);
        src += 4096;
    };

    __syncthreads();            // vnL visible to all waves
    stage(0);
    for (int ch = 0; ch < 8; ch++) {
        // chunk ch's loads landed; barrier; prefetch ch+1 into other buffer
        asm volatile("s_waitcnt vmcnt(0)" ::: "memory");
        __builtin_amdgcn_sched_barrier(0);
        __builtin_amdgcn_s_barrier();
        __builtin_amdgcn_sched_barrier(0);
        if (ch + 1 < 8) stage((ch + 1) & 1);
        #pragma unroll
        for (int hf = 0; hf < 2; hf++) {
            const _Float16* K = &Ksh[ch & 1][hf << 11];
            const _Float16* V = &Vsh[ch & 1][hf << 11];
            // K fragments (A-operand): rows = keys of this half-chunk
            const f16x8_t b00 = load_h8(&K[(m16 << 6) + s00]);
            const f16x8_t b01 = load_h8(&K[(m16 << 6) + s01]);
            const f16x8_t b10 = load_h8(&K[((16 + m16) << 6) + s00]);
            const f16x8_t b11 = load_h8(&K[((16 + m16) << 6) + s01]);
            // swapped QK^T: D[key][query]; c0/c1 rowset0, c2/c3 rowset1
            f32x4_t c0 = MFMAH(b00, a0, z); c0 = MFMAH(b01, a1, c0);
            f32x4_t c1 = MFMAH(b10, a0, z); c1 = MFMAH(b11, a1, c1);
            f32x4_t c2 = MFMAH(b00, a2, z); c2 = MFMAH(b01, a3, c2);
            f32x4_t c3 = MFMAH(b10, a2, z); c3 = MFMAH(b11, a3, c3);
            const int vb = (ch << 6) + (hf << 5);
            const f32x4_t vn0 = *reinterpret_cast<const f32x4_t*>(&vnL[vb + (quad << 2)]);
            const f32x4_t vn1 = *reinterpret_cast<const f32x4_t*>(&vnL[vb + 16 + (quad << 2)]);
            union { h16x2_t h2[4]; f16x8_t v8; } pk0, pk1;
            pk0.h2[0] = __builtin_amdgcn_cvt_pkrtz(
                __builtin_amdgcn_exp2f(fmaf(c0[0], KS, vn0[0])),
                __builtin_amdgcn_exp2f(fmaf(c0[1], KS, vn0[1])));
            pk0.h2[1] = __builtin_amdgcn_cvt_pkrtz(
                __builtin_amdgcn_exp2f(fmaf(c0[2], KS, vn0[2])),
                __builtin_amdgcn_exp2f(fmaf(c0[3], KS, vn0[3])));
            pk0.h2[2] = __builtin_amdgcn_cvt_pkrtz(
                __builtin_amdgcn_exp2f(fmaf(c1[0], KS, vn1[0])),
                __builtin_amdgcn_exp2f(fmaf(c1[1], KS, vn1[1])));
            pk0.h2[3] = __builtin_amdgcn_cvt_pkrtz(
                __builtin_amdgcn_exp2f(fmaf(c1[2], KS, vn1[2])),
                __builtin_amdgcn_exp2f(fmaf(c1[3], KS, vn1[3])));
            pk1.h2[0] = __builtin_amdgcn_cvt_pkrtz(
                __builtin_amdgcn_exp2f(fmaf(c2[0], KS, vn0[0])),
                __builtin_amdgcn_exp2f(fmaf(c2[1], KS, vn0[1])));
            pk1.h2[1] = __builtin_amdgcn_cvt_pkrtz(
                __builtin_amdgcn_exp2f(fmaf(c2[2], KS, vn0[2])),
                __builtin_amdgcn_exp2f(fmaf(c2[3], KS, vn0[3])));
            pk1.h2[2] = __builtin_amdgcn_cvt_pkrtz(
                __builtin_amdgcn_exp2f(fmaf(c3[0], KS, vn1[0])),
                __builtin_amdgcn_exp2f(fmaf(c3[1], KS, vn1[1])));
            pk1.h2[3] = __builtin_amdgcn_cvt_pkrtz(
                __builtin_amdgcn_exp2f(fmaf(c3[2], KS, vn1[2])),
                __builtin_amdgcn_exp2f(fmaf(c3[3], KS, vn1[3])));
            const f16x8_t pa0 = pk0.v8, pa1 = pk1.v8;
            lacc0 = MFMAH(pa0, ones, lacc0);
            lacc1 = MFMAH(pa1, ones, lacc1);
            #pragma unroll
            for (int nt = 0; nt < 4; nt++) {
                const f16x8_t vb2 = load_h8(&V[((nt * 16 + m16) << 5) + ((quad ^ vsw) << 3)]);
                xacc0[nt] = MFMAH(pa0, vb2, xacc0[nt]);
                xacc1[nt] = MFMAH(pa1, vb2, xacc1[nt]);
            }
        }
    }
    const int b = bh >> 3, h = bh & 7;
    if (m16 == 0) {
        #pragma unroll
        for (int r = 0; r < 4; r++) {
            lp[((size_t)ks << 15) + (bh << 11) + rowbase + (quad << 2) + r] = lacc0[r];
            lp[((size_t)ks << 15) + (bh << 11) + rowbase + 16 + (quad << 2) + r] = lacc1[r];
        }
    }
    const size_t xbase = ((size_t)ks << 21);
    #pragma unroll
    for (int r = 0; r < 4; r++) {
        const int row0 = rowbase + (quad << 2) + r;
        const int row1 = row0 + 16;
        #pragma unroll
        for (int nt = 0; nt < 4; nt++) {
            xp[xbase + (((size_t)(b << 11) + row0) << 9) + (h << 6) + (nt << 4) + m16] = xacc0[nt][r];
            xp[xbase + (((size_t)(b << 11) + row1) << 9) + (h << 6) + (nt << 4) + m16] = xacc1[nt][r];
        }
    }
}

// ---------------------------------------------------------------------------
// K4b: combine4 -- A = (xp0+xp1+xp2+xp3) * 1/(l0+l1+l2+l3), f16 hi/lo split,
// flat [4096][512]. Fully parallel, vectorized; takes the combine off
// out_gemm's latency-critical path.
// ---------------------------------------------------------------------------
__global__ __launch_bounds__(256) void combine4(
        const float* __restrict__ xp, const float* __restrict__ lp,
        _Float16* __restrict__ Ahi, _Float16* __restrict__ Alo)
{
    const int gid = blockIdx.x * 256 + threadIdx.x;    // 262144 = 4096*512/8
    const int r = gid >> 6, c8 = gid & 63;             // row, col-block of 8
    const int b = r >> 11, n = r & 2047, h = c8 >> 3;  // head = (c8*8)>>6
    const size_t li = ((size_t)((b << 3) + h) << 11) + n;
    const float linv = 1.0f / (lp[li] + lp[32768 + li] + lp[65536 + li] + lp[98304 + li]);
    const size_t o = (size_t)gid << 3;                 // f32 index into [4096][512]
    const float4* x0 = reinterpret_cast<const float4*>(xp + o);
    const float4* x1 = reinterpret_cast<const float4*>(xp + 2097152 + o);
    const float4* x2 = reinterpret_cast<const float4*>(xp + 4194304 + o);
    const float4* x3 = reinterpret_cast<const float4*>(xp + 6291456 + o);
    f16x8_t hv, lv;
    #pragma unroll
    for (int s = 0; s < 2; s++) {
        const float4 p0 = x0[s], p1 = x1[s], p2 = x2[s], p3 = x3[s];
        float vv[4];
        vv[0] = (p0.x + p1.x + p2.x + p3.x) * linv;
        vv[1] = (p0.y + p1.y + p2.y + p3.y) * linv;
        vv[2] = (p0.z + p1.z + p2.z + p3.z) * linv;
        vv[3] = (p0.w + p1.w + p2.w + p3.w) * linv;
        #pragma unroll
        for (int i = 0; i < 4; i++) {
            const _Float16 hh = (_Float16)vv[i];
            hv[s * 4 + i] = hh;
            lv[s * 4 + i] = (_Float16)(vv[i] - (float)hh);
        }
    }
    *reinterpret_cast<f16x8_t*>(Ahi + o) = hv;
    *reinterpret_cast<f16x8_t*>(Alo + o) = lv;
}

// ---------------------------------------------------------------------------
// K5: output GEMM. A read pre-combined/pre-split from Ahi/Alo (f16), pure
// vector loads; out[m,j] = sum_k A[m,k]*Wproj[j,k], fp32 out.
// ---------------------------------------------------------------------------
__global__ __launch_bounds__(256) void out_gemm(
        const _Float16* __restrict__ Ahi, const _Float16* __restrict__ Alo,
        const _Float16* __restrict__ Wh, const _Float16* __restrict__ Wl,
        float* __restrict__ outF)
{
    __shared__ __attribute__((aligned(16))) _Float16 Wsh[2][2][4096];  // 32 KB
    const int t = threadIdx.x, w = t >> 6, lane = t & 63;
    const int m16 = lane & 15, quad = lane >> 4;
    const int bm = blockIdx.x << 7, bn = blockIdx.y << 6;
    const int r0 = bm + (w << 5) + m16, r1 = r0 + 16;
    const int krow = lane >> 3, kblk = (lane & 7) ^ (krow & 7);
    const int e = m16 & 7;
    const int s00 = (quad ^ e) << 3, s01 = ((4 + quad) ^ e) << 3;
    const f32x4_t z = {0.f, 0.f, 0.f, 0.f};
    f32x4_t acc[2][4];
    #pragma unroll
    for (int rs = 0; rs < 2; rs++)
        #pragma unroll
        for (int tl = 0; tl < 4; tl++) acc[rs][tl] = z;

    auto stageW = [&](int buf, int kc) {
        #pragma unroll
        for (int ci = 0; ci < 4; ci++) {
            const int pp = (w << 2) + ci;
            const int s = pp >> 3, pj = pp & 7;
            const _Float16* src = (s ? Wl : Wh)
                + (size_t)(bn + (pj << 3) + krow) * C_ + kc + (kblk << 3);
            gload_lds16(src, &Wsh[buf][s][pj << 9]);
        }
    };
    auto loadA = [&](int ch, f16x8_t* d) {
        const int kc = ch << 6;                       // head = ch
        #pragma unroll
        for (int rs = 0; rs < 2; rs++) {
            const size_t base = ((size_t)(rs ? r1 : r0) << 9) + kc + (quad << 3);
            d[rs * 4 + 0] = load_h8(Ahi + base);
            d[rs * 4 + 1] = load_h8(Ahi + base + 32);
            d[rs * 4 + 2] = load_h8(Alo + base);
            d[rs * 4 + 3] = load_h8(Alo + base + 32);
        }
    };

    f16x8_t cA[8], nA[8];
    stageW(0, 0);
    loadA(0, cA);
    for (int ch = 0; ch < 8; ch++) {
        __syncthreads();
        if (ch + 1 < 8) {
            stageW((ch + 1) & 1, (ch + 1) << 6);
            loadA(ch + 1, nA);
        }
        const _Float16* W0 = Wsh[ch & 1][0];
        const _Float16* W1 = Wsh[ch & 1][1];
        #pragma unroll
        for (int tl = 0; tl < 4; tl++) {
            const int j64 = ((tl << 4) + m16) << 6;
            const f16x8_t bh0 = load_h8(&W0[j64 + s00]);
            const f16x8_t bh1 = load_h8(&W0[j64 + s01]);
            const f16x8_t bl0 = load_h8(&W1[j64 + s00]);
            const f16x8_t bl1 = load_h8(&W1[j64 + s01]);
            f32x4_t c0 = acc[0][tl];
            c0 = MFMAH(cA[0], bh0, c0); c0 = MFMAH(cA[1], bh1, c0);
            c0 = MFMAH(cA[2], bh0, c0); c0 = MFMAH(cA[3], bh1, c0);
            c0 = MFMAH(cA[0], bl0, c0); c0 = MFMAH(cA[1], bl1, c0);
            acc[0][tl] = c0;
            f32x4_t c1 = acc[1][tl];
            c1 = MFMAH(cA[4], bh0, c1); c1 = MFMAH(cA[5], bh1, c1);
            c1 = MFMAH(cA[6], bh0, c1); c1 = MFMAH(cA[7], bh1, c1);
            c1 = MFMAH(cA[4], bl0, c1); c1 = MFMAH(cA[5], bl1, c1);
            acc[1][tl] = c1;
        }
        #pragma unroll
        for (int i = 0; i < 8; i++) cA[i] = nA[i];
    }
    #pragma unroll
    for (int rs = 0; rs < 2; rs++) {
        #pragma unroll
        for (int tl = 0; tl < 4; tl++) {
            #pragma unroll
            for (int r = 0; r < 4; r++) {
                const int gr = bm + (w << 5) + (rs << 4) + (quad << 2) + r;
                const int gj = bn + (tl << 4) + m16;
                outF[(size_t)gr * C_ + gj] = acc[rs][tl][r];
            }
        }
    }
}

// ---------------------------------------------------------------------------
extern "C" void kernel_launch(void* const* d_in, const int* in_sizes, int n_in,
                              void* d_out, int out_size, void* d_ws, size_t ws_size,
                              hipStream_t stream) {
    const float* q  = (const float*)d_in[0];
    const float* k  = (const float*)d_in[1];
    const float* v  = (const float*)d_in[2];
    const float* supp_valid = (const float*)d_in[3];
    const int*   supp_mask  = (const int*)d_in[4];
    const float* Wq = (const float*)d_in[5];
    const float* Wk = (const float*)d_in[6];
    const float* Wv = (const float*)d_in[7];
    const float* Wp = (const float*)d_in[8];
    float* out = (float*)d_out;

    char* p = (char*)d_ws;
    _Float16* qhi = (_Float16*)p;      p += 4194304;   // [bh][n][d] f16 splits
    _Float16* qlo = (_Float16*)p;      p += 4194304;
    _Float16* khi = (_Float16*)p;      p += 4194304;
    _Float16* klo = (_Float16*)p;      p += 4194304;
    _Float16* vT  = (_Float16*)p;      p += 4194304;   // [bh] chunk-tiled (k')
    float* xp     = (float*)p;         p += 33554432;  // [4][4096][512] f32
    _Float16* wH  = (_Float16*)p;      p += 2097152;   // [4][512*512]
    _Float16* wL  = (_Float16*)p;      p += 2097152;
    _Float16* Ahi = (_Float16*)p;      p += 4194304;   // [4096][512] f16
    _Float16* Alo = (_Float16*)p;      p += 4194304;
    unsigned long long* q2kP = (unsigned long long*)p; p += 262144;
    unsigned long long* k2qP = (unsigned long long*)p; p += 262144;
    float* lp = (float*)p;             p += 524288;    // [4][16][2048]

    (void)hipMemsetAsync(q2kP, 0, 524288, stream);     // rowP + colP zero init

    dim3 bG(256);
    wsplit4<<<dim3(256, 4), bG, 0, stream>>>(Wq, Wk, Wv, Wp, wH, wL);
    proj_gemm<<<dim3(32, 8, 3), bG, 0, stream>>>(q, k, v, wH, wL,
                                                 qhi, qlo, khi, klo, vT);

    argmax_mfma<<<1024, bG, 0, stream>>>(qhi, qlo, khi, klo, q2kP, k2qP);

    attn_pv<<<1024, bG, 0, stream>>>(qhi, khi, vT, q2kP, k2qP,
                                     supp_mask, supp_valid, xp, lp);

    combine4<<<1024, bG, 0, stream>>>(xp, lp, Ahi, Alo);

    out_gemm<<<dim3(32, 8), bG, 0, stream>>>(Ahi, Alo,
                                             wH + 3 * 262144, wL + 3 * 262144, out);
}

// Round 15
// 195.531 us; speedup vs baseline: 1.0702x; 1.0558x over previous
//
#include <hip/hip_runtime.h>
#include <hip/hip_bf16.h>
#include <stdint.h>

#define H_ 8
#define NS_ 2048
#define C_ 512
#define HD_ 64
#define SCALE_ 0.125f
#define NEG_ -10000.0f
#define LOG2E_ 1.4426950408889634f
#define MFIX_ 4.0f

typedef _Float16 f16x8_t __attribute__((ext_vector_type(8)));
typedef _Float16 f16x4_t __attribute__((ext_vector_type(4)));
typedef __fp16 h16x2_t __attribute__((ext_vector_type(2)));   // cvt_pkrtz ret type
typedef float f32x4_t __attribute__((ext_vector_type(4)));

#define MFMAH(a, b, c) __builtin_amdgcn_mfma_f32_16x16x32_f16(a, b, c, 0, 0, 0)

__device__ inline f16x8_t load_h8(const _Float16* p) {
    return *reinterpret_cast<const f16x8_t*>(p);
}

// async global->LDS, 16B per lane; LDS dest = uniform base + lane*16
__device__ inline void gload_lds16(const void* g, void* l) {
    __builtin_amdgcn_global_load_lds(
        (const __attribute__((address_space(1))) unsigned int*)g,
        (__attribute__((address_space(3))) unsigned int*)l, 16, 0, 0);
}

__device__ inline unsigned orderF(float v) {
    unsigned u = __float_as_uint(v);
    return (u & 0x80000000u) ? ~u : (u | 0x80000000u);
}
__device__ inline unsigned long long packVR(float v, int idx) {
    return ((unsigned long long)orderF(v) << 32) | (unsigned)(~idx);
}
__device__ inline unsigned long long max64(unsigned long long a, unsigned long long b) {
    return a > b ? a : b;
}
__device__ inline unsigned long long shflx64(unsigned long long x, int m) {
    unsigned lo = (unsigned)x, hi = (unsigned)(x >> 32);
    lo = __shfl_xor(lo, m, 64);
    hi = __shfl_xor(hi, m, 64);
    return ((unsigned long long)hi << 32) | lo;
}

// ---------------------------------------------------------------------------
// K0: all four 512x512 weights -> f16 hi/lo splits in one launch.
// ---------------------------------------------------------------------------
__global__ __launch_bounds__(256) void wsplit4(
        const float* __restrict__ w0, const float* __restrict__ w1,
        const float* __restrict__ w2, const float* __restrict__ w3,
        _Float16* __restrict__ hi, _Float16* __restrict__ lo)
{
    const int i = blockIdx.x * 256 + threadIdx.x;            // 65536 float4 / W
    const int y = blockIdx.y;
    const float* src = (y == 0) ? w0 : (y == 1) ? w1 : (y == 2) ? w2 : w3;
    const float4 v = reinterpret_cast<const float4*>(src)[i];
    f16x4_t hv, lv;
    hv[0] = (_Float16)v.x; hv[1] = (_Float16)v.y;
    hv[2] = (_Float16)v.z; hv[3] = (_Float16)v.w;
    lv[0] = (_Float16)(v.x - (float)hv[0]);
    lv[1] = (_Float16)(v.y - (float)hv[1]);
    lv[2] = (_Float16)(v.z - (float)hv[2]);
    lv[3] = (_Float16)(v.w - (float)hv[3]);
    const size_t o = ((size_t)y << 16) + i;                  // float4 index
    reinterpret_cast<f16x4_t*>(hi)[o] = hv;
    reinterpret_cast<f16x4_t*>(lo)[o] = lv;
}

// ---------------------------------------------------------------------------
// K1: projection GEMM (q/k/v via grid.z). 3-term split-f16 MFMA (~fp32).
// z<2: hi/lo split out [bh][n][d]; z==2: V tiled [bh][key>>5][d][k'] with
// k' = ((key>>2)&3)<<3 | ((key>>4)&1)<<2 | (key&3)
// (chosen so attn_pv's in-register P fragment k-slot quad*8+i hits its keys).
// ---------------------------------------------------------------------------
__global__ __launch_bounds__(256) void proj_gemm(
        const float* __restrict__ qin, const float* __restrict__ kin,
        const float* __restrict__ vin,
        const _Float16* __restrict__ wHall, const _Float16* __restrict__ wLall,
        _Float16* __restrict__ qhi, _Float16* __restrict__ qlo,
        _Float16* __restrict__ khi, _Float16* __restrict__ klo,
        _Float16* __restrict__ vT)
{
    __shared__ __attribute__((aligned(16))) _Float16 Wsh[2][2][4096];  // 32 KB
    const int zz = blockIdx.z;
    const float* A32 = (zz == 0) ? qin : (zz == 1) ? kin : vin;
    const _Float16* Wh = wHall + ((size_t)zz << 18);
    const _Float16* Wl = wLall + ((size_t)zz << 18);
    const int t = threadIdx.x, w = t >> 6, lane = t & 63;
    const int m16 = lane & 15, quad = lane >> 4;
    const int bm = blockIdx.x << 7, bn = blockIdx.y << 6;
    const int r0 = bm + (w << 5) + m16, r1 = r0 + 16;
    const int krow = lane >> 3, kblk = (lane & 7) ^ (krow & 7);
    const int e = m16 & 7;
    const int s00 = (quad ^ e) << 3, s01 = ((4 + quad) ^ e) << 3;
    const f32x4_t z = {0.f, 0.f, 0.f, 0.f};
    f32x4_t acc[2][4];
    #pragma unroll
    for (int rs = 0; rs < 2; rs++)
        #pragma unroll
        for (int tl = 0; tl < 4; tl++) acc[rs][tl] = z;

    auto stageW = [&](int buf, int kc) {
        #pragma unroll
        for (int ci = 0; ci < 4; ci++) {
            const int pp = (w << 2) + ci;
            const int s = pp >> 3, pj = pp & 7;
            const _Float16* src = (s ? Wl : Wh)
                + (size_t)(bn + (pj << 3) + krow) * C_ + kc + (kblk << 3);
            gload_lds16(src, &Wsh[buf][s][pj << 9]);
        }
    };
    auto loadA = [&](int kc, f16x8_t* d) {
        #pragma unroll
        for (int rs = 0; rs < 2; rs++) {
            const float* pr = A32 + (size_t)(rs ? r1 : r0) * C_ + kc + (quad << 3);
            #pragma unroll
            for (int seg = 0; seg < 2; seg++) {
                f16x8_t hv, lv;
                #pragma unroll
                for (int i = 0; i < 8; i++) {
                    const float x = pr[seg * 32 + i];
                    const _Float16 hh = (_Float16)x;
                    hv[i] = hh;
                    lv[i] = (_Float16)(x - (float)hh);
                }
                d[rs * 4 + seg] = hv;
                d[rs * 4 + seg + 2] = lv;
            }
        }
    };

    f16x8_t cA[8], nA[8];
    stageW(0, 0);
    loadA(0, cA);
    for (int ch = 0; ch < 8; ch++) {
        __syncthreads();
        if (ch + 1 < 8) {
            stageW((ch + 1) & 1, (ch + 1) << 6);
            loadA((ch + 1) << 6, nA);
        }
        const _Float16* W0 = Wsh[ch & 1][0];
        const _Float16* W1 = Wsh[ch & 1][1];
        #pragma unroll
        for (int tl = 0; tl < 4; tl++) {
            const int j64 = ((tl << 4) + m16) << 6;
            const f16x8_t bh0 = load_h8(&W0[j64 + s00]);
            const f16x8_t bh1 = load_h8(&W0[j64 + s01]);
            const f16x8_t bl0 = load_h8(&W1[j64 + s00]);
            const f16x8_t bl1 = load_h8(&W1[j64 + s01]);
            f32x4_t c0 = acc[0][tl];
            c0 = MFMAH(cA[0], bh0, c0); c0 = MFMAH(cA[1], bh1, c0);
            c0 = MFMAH(cA[2], bh0, c0); c0 = MFMAH(cA[3], bh1, c0);
            c0 = MFMAH(cA[0], bl0, c0); c0 = MFMAH(cA[1], bl1, c0);
            acc[0][tl] = c0;
            f32x4_t c1 = acc[1][tl];
            c1 = MFMAH(cA[4], bh0, c1); c1 = MFMAH(cA[5], bh1, c1);
            c1 = MFMAH(cA[6], bh0, c1); c1 = MFMAH(cA[7], bh1, c1);
            c1 = MFMAH(cA[4], bl0, c1); c1 = MFMAH(cA[5], bl1, c1);
            acc[1][tl] = c1;
        }
        #pragma unroll
        for (int i = 0; i < 8; i++) cA[i] = nA[i];
    }
    const int by = blockIdx.y;
    _Float16* o1 = (zz == 0) ? qhi : khi;
    _Float16* o2 = (zz == 0) ? qlo : klo;
    #pragma unroll
    for (int rs = 0; rs < 2; rs++) {
        #pragma unroll
        for (int tl = 0; tl < 4; tl++) {
            #pragma unroll
            for (int r = 0; r < 4; r++) {
                const int gr = bm + (w << 5) + (rs << 4) + (quad << 2) + r;
                const float val = acc[rs][tl][r];
                const int b = gr >> 11, n = gr & 2047;
                const int d = (tl << 4) + m16;
                const int bh = (b << 3) + by;
                if (zz == 2) {
                    const int kp = (((n >> 2) & 3) << 3) | (((n >> 4) & 1) << 2) | (n & 3);
                    vT[(((size_t)((bh << 6) + (n >> 5)) << 6) + d) * 32 + kp] = (_Float16)val;
                } else {
                    const size_t idx = ((((size_t)bh << 11) + n) << 6) + d;
                    const _Float16 hh = (_Float16)val;
                    o1[idx] = hh;
                    o2[idx] = (_Float16)(val - (float)hh);
                }
            }
        }
    }
}

// ---------------------------------------------------------------------------
// K2: MFMA split-f16 argmax. 64-key chunks, 4-tl, single-buffered LDS,
// key-split x4 -> 1024 blocks. Col-argmax: per-(col,quad) partial is written
// ONCE per block -> plain ds_write to colq[512][4] (no butterfly shuffles,
// no LDS atomics, no divergent quad==0 path -- removes 2 chained shflx64 +
// 1 LDS atomic per tl-iter), reduced post-loop with 3 max64 + global
// atomicMax. packVR max is commutative/associative -> bit-identical result.
// ---------------------------------------------------------------------------
__global__ __launch_bounds__(256) void argmax_mfma(
        const _Float16* __restrict__ qhi, const _Float16* __restrict__ qlo,
        const _Float16* __restrict__ khi, const _Float16* __restrict__ klo,
        unsigned long long* __restrict__ rowP, unsigned long long* __restrict__ colP)
{
    __shared__ __attribute__((aligned(16))) _Float16 Ksh[2][4096];     // 16 KB
    __shared__ __attribute__((aligned(16))) unsigned long long colq[512][4]; // 16 KB
    const int bx = blockIdx.x;
    const int bh = ((bx & 7) << 1) | (bx >> 9);            // 1024 blocks
    const int mid = (bx >> 3) & 63;
    const int rt = mid & 15;
    const int ks = mid >> 4;                               // 0..3, 512 keys
    const int t = threadIdx.x, w = t >> 6, lane = t & 63;
    const int m16 = lane & 15, quad = lane >> 4;
    const int wrow = (rt << 7) + (w << 5);
    const size_t qoff0 = ((((size_t)bh << 11) + wrow + m16) << 6) + (quad << 3);
    const size_t qoff1 = qoff0 + 1024;
    const f16x8_t a00h = load_h8(qhi + qoff0), a01h = load_h8(qhi + qoff0 + 32);
    const f16x8_t a00l = load_h8(qlo + qoff0), a01l = load_h8(qlo + qoff0 + 32);
    const f16x8_t a10h = load_h8(qhi + qoff1), a11h = load_h8(qhi + qoff1 + 32);
    const f16x8_t a10l = load_h8(qlo + qoff1), a11l = load_h8(qlo + qoff1 + 32);
    const int krow = lane >> 3, kblk = (lane & 7) ^ (krow & 7);
    const int e = m16 & 7;
    const int s00 = (quad ^ e) << 3, s01 = ((4 + quad) ^ e) << 3;
    const size_t kbase = (((size_t)bh << 11) + (ks << 9)) << 6;
    float bv0[4] = {-3.4e38f, -3.4e38f, -3.4e38f, -3.4e38f};
    float bv1[4] = {-3.4e38f, -3.4e38f, -3.4e38f, -3.4e38f};
    int bc0[4] = {0, 0, 0, 0}, bc1[4] = {0, 0, 0, 0};
    const f32x4_t z = {0.f, 0.f, 0.f, 0.f};
    // per-wave max over the rows this wave owns; wave w owns a distinct
    // 32-row stripe, so each (col,quad) partial is private to this wave.
    unsigned long long* myq = &colq[0][0];

    auto stage = [&](int cidx) {
        const size_t ce = kbase + ((size_t)cidx << 12);
        #pragma unroll
        for (int ci = 0; ci < 4; ci++) {
            const int pp = (w << 2) + ci;
            const int s = pp >> 3, pj = pp & 7;
            const _Float16* src = (s ? klo : khi) + ce + (((pj << 3) + krow) << 6) + (kblk << 3);
            gload_lds16(src, &Ksh[s][pj << 9]);
        }
    };

    // NOTE: 4 waves each produce a (col,quad) partial for the SAME column
    // range -- they must still be merged across waves. Keep a per-wave
    // in-register running merge instead: each lane's (tl,m16) column at
    // chunk ch is distinct per iteration, so the partial is written to
    // colq[col][quad] with an LDS atomicMax ONLY across the 4 waves
    // (same-slot contention = 4, down from 16 with no butterfly chain).
    for (int c = t; c < 512; c += 256) {
        colq[c][0] = 0; colq[c][1] = 0; colq[c][2] = 0; colq[c][3] = 0;
    }

    for (int ch = 0; ch < 8; ch++) {
        __syncthreads();                          // prior compute done
        stage(ch);
        asm volatile("s_waitcnt vmcnt(0)" ::: "memory");
        __syncthreads();                          // chunk staged for all waves
        const _Float16* K0 = Ksh[0];
        const _Float16* K1 = Ksh[1];
        const int kc0 = (ks << 9) + (ch << 6);
        #pragma unroll
        for (int tl = 0; tl < 4; tl++) {
            const int j64 = ((tl << 4) + m16) << 6;
            const f16x8_t bh0 = load_h8(&K0[j64 + s00]);
            const f16x8_t bh1 = load_h8(&K0[j64 + s01]);
            const f16x8_t bl0 = load_h8(&K1[j64 + s00]);
            const f16x8_t bl1 = load_h8(&K1[j64 + s01]);
            f32x4_t c0 = MFMAH(a00h, bh0, z);
            c0 = MFMAH(a01h, bh1, c0);
            c0 = MFMAH(a00l, bh0, c0); c0 = MFMAH(a01l, bh1, c0);
            c0 = MFMAH(a00h, bl0, c0); c0 = MFMAH(a01h, bl1, c0);
            f32x4_t c1 = MFMAH(a10h, bh0, z);
            c1 = MFMAH(a11h, bh1, c1);
            c1 = MFMAH(a10l, bh0, c1); c1 = MFMAH(a11l, bh1, c1);
            c1 = MFMAH(a10h, bl0, c1); c1 = MFMAH(a11h, bl1, c1);
            const int gc = kc0 + (tl << 4) + m16;
            #pragma unroll
            for (int r = 0; r < 4; r++) {
                if (c0[r] > bv0[r]) { bv0[r] = c0[r]; bc0[r] = gc; }
                if (c1[r] > bv1[r]) { bv1[r] = c1[r]; bc1[r] = gc; }
            }
            // col argmax: in-lane over 8 rows (rowset0 first -> smallest row)
            float v = c0[0]; int ri = (quad << 2);
            if (c0[1] > v) { v = c0[1]; ri = (quad << 2) + 1; }
            if (c0[2] > v) { v = c0[2]; ri = (quad << 2) + 2; }
            if (c0[3] > v) { v = c0[3]; ri = (quad << 2) + 3; }
            if (c1[0] > v) { v = c1[0]; ri = 16 + (quad << 2); }
            if (c1[1] > v) { v = c1[1]; ri = 16 + (quad << 2) + 1; }
            if (c1[2] > v) { v = c1[2]; ri = 16 + (quad << 2) + 2; }
            if (c1[3] > v) { v = c1[3]; ri = 16 + (quad << 2) + 3; }
            // plain-slot partial per (col, quad); 4-wave contention only
            atomicMax(&colq[(ch << 6) + (tl << 4) + m16][quad],
                      packVR(v, wrow + ri));
        }
    }
    #pragma unroll
    for (int r = 0; r < 4; r++) {
        unsigned long long p0 = packVR(bv0[r], bc0[r]);
        p0 = max64(p0, shflx64(p0, 1)); p0 = max64(p0, shflx64(p0, 2));
        p0 = max64(p0, shflx64(p0, 4)); p0 = max64(p0, shflx64(p0, 8));
        if (m16 == 0)
            atomicMax(rowP + ((size_t)bh << 11) + wrow + (quad << 2) + r, p0);
        unsigned long long p1 = packVR(bv1[r], bc1[r]);
        p1 = max64(p1, shflx64(p1, 1)); p1 = max64(p1, shflx64(p1, 2));
        p1 = max64(p1, shflx64(p1, 4)); p1 = max64(p1, shflx64(p1, 8));
        if (m16 == 0)
            atomicMax(rowP + ((size_t)bh << 11) + wrow + 16 + (quad << 2) + r, p1);
    }
    __syncthreads();
    for (int c = t; c < 512; c += 256) {
        unsigned long long m = max64(max64(colq[c][0], colq[c][1]),
                                     max64(colq[c][2], colq[c][3]));
        atomicMax(colP + ((size_t)bh << 11) + (ks << 9) + c, m);
    }
    (void)myq;
}

// ---------------------------------------------------------------------------
// K4: fused attention, swapped-QK^T form, resolve fused into vnL prologue.
// 32 rows/wave, key-split x4 -> 1024 blocks = 4/CU. 64-key chunks (8
// barriers), ring-2 LDS + prefetch depth 1. [round-10 version: best measured]
// ---------------------------------------------------------------------------
__global__ __launch_bounds__(256, 4) void attn_pv(
        const _Float16* __restrict__ qh, const _Float16* __restrict__ kh,
        const _Float16* __restrict__ vT,
        const unsigned long long* __restrict__ q2kP,
        const unsigned long long* __restrict__ k2qP,
        const int* __restrict__ supp_mask,
        const float* __restrict__ supp_valid,
        float* __restrict__ xp, float* __restrict__ lp)
{
    __shared__ __attribute__((aligned(16))) _Float16 Ksh[2][4096];    // 16 KB
    __shared__ __attribute__((aligned(16))) _Float16 Vsh[2][4096];    // 16 KB
    __shared__ __attribute__((aligned(16))) float vnL[512];           // 2 KB
    const int bx = blockIdx.x;
    const int bh = ((bx & 7) << 1) | (bx >> 9);            // 1024 blocks
    const int mid = (bx >> 3) & 63;
    const int rt = mid & 15, ks = mid >> 4;                // ks 0..3, 512 keys
    const int t = threadIdx.x, w = t >> 6, lane = t & 63;
    const int m16 = lane & 15, quad = lane >> 4;
    const int rowbase = (rt << 7) + (w << 5);              // 32 rows/wave
    const size_t qoff = ((((size_t)bh << 11) + rowbase + m16) << 6) + (quad << 3);
    const f16x8_t a0 = load_h8(qh + qoff), a1 = load_h8(qh + qoff + 32);
    const f16x8_t a2 = load_h8(qh + qoff + 1024), a3 = load_h8(qh + qoff + 1056);
    // fused resolve: vn[j] = (asso ? supp_valid : 1) * NEG * LOG2E - MFIX
    {
        const int b = bh >> 3;
        for (int c = t; c < 512; c += 256) {
            const int j = (ks << 9) + c;
            const unsigned k2q = 0xFFFFFFFFu
                - (unsigned)(k2qP[(bh << 11) + j] & 0xFFFFFFFFull);
            const unsigned rm = 0xFFFFFFFFu
                - (unsigned)(q2kP[(bh << 11) + (int)k2q] & 0xFFFFFFFFull);
            const int asso = supp_mask[(b << 11) + j] == supp_mask[(b << 11) + (int)rm];
            const float valid = asso ? supp_valid[(b << 11) + j] : 1.0f;
            vnL[c] = fmaf(valid, NEG_ * LOG2E_, -MFIX_);
        }
    }
    const float KS = SCALE_ * LOG2E_;
    const int krow = lane >> 3, kblk = (lane & 7) ^ ((lane >> 3) & 7);
    const int vrow = lane >> 2, vblk = (lane & 3) ^ ((lane >> 3) & 3);
    const int e = m16 & 7;
    const int s00 = (quad ^ e) << 3, s01 = ((4 + quad) ^ e) << 3;
    const int vsw = (m16 >> 1) & 3;
    f16x8_t ones;
    #pragma unroll
    for (int i = 0; i < 8; i++) ones[i] = (_Float16)1.0f;
    const f32x4_t z = {0.f, 0.f, 0.f, 0.f};
    f32x4_t xacc0[4], xacc1[4];
    #pragma unroll
    for (int nt = 0; nt < 4; nt++) { xacc0[nt] = z; xacc1[nt] = z; }
    f32x4_t lacc0 = z, lacc1 = z;

    // staging: waves 0-1 stage K (wave w -> keys 32w..32w+31), waves 2-3
    // stage V (wave w-2 -> 32-key tile w-2); 4 gload_lds per thread per
    // 64-key chunk, contiguous 2048-half span each; src steps 4096/chunk.
    const size_t kbel = ((size_t)bh << 11) * HD_;
    const bool isK = (w < 2);
    const _Float16* src;
    _Float16* dstBase;
    if (isK) {
        src = kh + kbel + ((size_t)ks << 15) + (w << 11) + (krow << 6) + (kblk << 3);
        dstBase = &Ksh[0][w << 11];
    } else {
        src = vT + (((size_t)(bh << 6) + (ks << 4)) << 11)
                 + ((w - 2) << 11) + (vrow << 5) + (vblk << 3);
        dstBase = &Vsh[0][(w - 2) << 11];
    }
    auto stage = [&](int bufidx) {
        _Float16* d = dstBase + (bufidx << 12);
        gload_lds16(src, d);
        gload_lds16(src + 512, d + 512);
        gload_lds16(src + 1024, d + 1024);
        gload_lds16(src + 1536, d + 1536);
        src += 4096;
    };

    __syncthreads();            // vnL visible to all waves
    stage(0);
    for (int ch = 0; ch < 8; ch++) {
        // chunk ch's loads landed; barrier; prefetch ch+1 into other buffer
        asm volatile("s_waitcnt vmcnt(0)" ::: "memory");
        __builtin_amdgcn_sched_barrier(0);
        __builtin_amdgcn_s_barrier();
        __builtin_amdgcn_sched_barrier(0);
        if (ch + 1 < 8) stage((ch + 1) & 1);
        #pragma unroll
        for (int hf = 0; hf < 2; hf++) {
            const _Float16* K = &Ksh[ch & 1][hf << 11];
            const _Float16* V = &Vsh[ch & 1][hf << 11];
            // K fragments (A-operand): rows = keys of this half-chunk
            const f16x8_t b00 = load_h8(&K[(m16 << 6) + s00]);
            const f16x8_t b01 = load_h8(&K[(m16 << 6) + s01]);
            const f16x8_t b10 = load_h8(&K[((16 + m16) << 6) + s00]);
            const f16x8_t b11 = load_h8(&K[((16 + m16) << 6) + s01]);
            // swapped QK^T: D[key][query]; c0/c1 rowset0, c2/c3 rowset1
            f32x4_t c0 = MFMAH(b00, a0, z); c0 = MFMAH(b01, a1, c0);
            f32x4_t c1 = MFMAH(b10, a0, z); c1 = MFMAH(b11, a1, c1);
            f32x4_t c2 = MFMAH(b00, a2, z); c2 = MFMAH(b01, a3, c2);
            f32x4_t c3 = MFMAH(b10, a2, z); c3 = MFMAH(b11, a3, c3);
            const int vb = (ch << 6) + (hf << 5);
            const f32x4_t vn0 = *reinterpret_cast<const f32x4_t*>(&vnL[vb + (quad << 2)]);
            const f32x4_t vn1 = *reinterpret_cast<const f32x4_t*>(&vnL[vb + 16 + (quad << 2)]);
            union { h16x2_t h2[4]; f16x8_t v8; } pk0, pk1;
            pk0.h2[0] = __builtin_amdgcn_cvt_pkrtz(
                __builtin_amdgcn_exp2f(fmaf(c0[0], KS, vn0[0])),
                __builtin_amdgcn_exp2f(fmaf(c0[1], KS, vn0[1])));
            pk0.h2[1] = __builtin_amdgcn_cvt_pkrtz(
                __builtin_amdgcn_exp2f(fmaf(c0[2], KS, vn0[2])),
                __builtin_amdgcn_exp2f(fmaf(c0[3], KS, vn0[3])));
            pk0.h2[2] = __builtin_amdgcn_cvt_pkrtz(
                __builtin_amdgcn_exp2f(fmaf(c1[0], KS, vn1[0])),
                __builtin_amdgcn_exp2f(fmaf(c1[1], KS, vn1[1])));
            pk0.h2[3] = __builtin_amdgcn_cvt_pkrtz(
                __builtin_amdgcn_exp2f(fmaf(c1[2], KS, vn1[2])),
                __builtin_amdgcn_exp2f(fmaf(c1[3], KS, vn1[3])));
            pk1.h2[0] = __builtin_amdgcn_cvt_pkrtz(
                __builtin_amdgcn_exp2f(fmaf(c2[0], KS, vn0[0])),
                __builtin_amdgcn_exp2f(fmaf(c2[1], KS, vn0[1])));
            pk1.h2[1] = __builtin_amdgcn_cvt_pkrtz(
                __builtin_amdgcn_exp2f(fmaf(c2[2], KS, vn0[2])),
                __builtin_amdgcn_exp2f(fmaf(c2[3], KS, vn0[3])));
            pk1.h2[2] = __builtin_amdgcn_cvt_pkrtz(
                __builtin_amdgcn_exp2f(fmaf(c3[0], KS, vn1[0])),
                __builtin_amdgcn_exp2f(fmaf(c3[1], KS, vn1[1])));
            pk1.h2[3] = __builtin_amdgcn_cvt_pkrtz(
                __builtin_amdgcn_exp2f(fmaf(c3[2], KS, vn1[2])),
                __builtin_amdgcn_exp2f(fmaf(c3[3], KS, vn1[3])));
            const f16x8_t pa0 = pk0.v8, pa1 = pk1.v8;
            lacc0 = MFMAH(pa0, ones, lacc0);
            lacc1 = MFMAH(pa1, ones, lacc1);
            #pragma unroll
            for (int nt = 0; nt < 4; nt++) {
                const f16x8_t vb2 = load_h8(&V[((nt * 16 + m16) << 5) + ((quad ^ vsw) << 3)]);
                xacc0[nt] = MFMAH(pa0, vb2, xacc0[nt]);
                xacc1[nt] = MFMAH(pa1, vb2, xacc1[nt]);
            }
        }
    }
    const int b = bh >> 3, h = bh & 7;
    if (m16 == 0) {
        #pragma unroll
        for (int r = 0; r < 4; r++) {
            lp[((size_t)ks << 15) + (bh << 11) + rowbase + (quad << 2) + r] = lacc0[r];
            lp[((size_t)ks << 15) + (bh << 11) + rowbase + 16 + (quad << 2) + r] = lacc1[r];
        }
    }
    const size_t xbase = ((size_t)ks << 21);
    #pragma unroll
    for (int r = 0; r < 4; r++) {
        const int row0 = rowbase + (quad << 2) + r;
        const int row1 = row0 + 16;
        #pragma unroll
        for (int nt = 0; nt < 4; nt++) {
            xp[xbase + (((size_t)(b << 11) + row0) << 9) + (h << 6) + (nt << 4) + m16] = xacc0[nt][r];
            xp[xbase + (((size_t)(b << 11) + row1) << 9) + (h << 6) + (nt << 4) + m16] = xacc1[nt][r];
        }
    }
}

// ---------------------------------------------------------------------------
// K4b: combine4 -- A = (xp0+xp1+xp2+xp3) * 1/(l0+l1+l2+l3), f16 hi/lo split,
// flat [4096][512]. Fully parallel, vectorized; takes the combine off
// out_gemm's latency-critical path.
// ---------------------------------------------------------------------------
__global__ __launch_bounds__(256) void combine4(
        const float* __restrict__ xp, const float* __restrict__ lp,
        _Float16* __restrict__ Ahi, _Float16* __restrict__ Alo)
{
    const int gid = blockIdx.x * 256 + threadIdx.x;    // 262144 = 4096*512/8
    const int r = gid >> 6, c8 = gid & 63;             // row, col-block of 8
    const int b = r >> 11, n = r & 2047, h = c8 >> 3;  // head = (c8*8)>>6
    const size_t li = ((size_t)((b << 3) + h) << 11) + n;
    const float linv = 1.0f / (lp[li] + lp[32768 + li] + lp[65536 + li] + lp[98304 + li]);
    const size_t o = (size_t)gid << 3;                 // f32 index into [4096][512]
    const float4* x0 = reinterpret_cast<const float4*>(xp + o);
    const float4* x1 = reinterpret_cast<const float4*>(xp + 2097152 + o);
    const float4* x2 = reinterpret_cast<const float4*>(xp + 4194304 + o);
    const float4* x3 = reinterpret_cast<const float4*>(xp + 6291456 + o);
    f16x8_t hv, lv;
    #pragma unroll
    for (int s = 0; s < 2; s++) {
        const float4 p0 = x0[s], p1 = x1[s], p2 = x2[s], p3 = x3[s];
        float vv[4];
        vv[0] = (p0.x + p1.x + p2.x + p3.x) * linv;
        vv[1] = (p0.y + p1.y + p2.y + p3.y) * linv;
        vv[2] = (p0.z + p1.z + p2.z + p3.z) * linv;
        vv[3] = (p0.w + p1.w + p2.w + p3.w) * linv;
        #pragma unroll
        for (int i = 0; i < 4; i++) {
            const _Float16 hh = (_Float16)vv[i];
            hv[s * 4 + i] = hh;
            lv[s * 4 + i] = (_Float16)(vv[i] - (float)hh);
        }
    }
    *reinterpret_cast<f16x8_t*>(Ahi + o) = hv;
    *reinterpret_cast<f16x8_t*>(Alo + o) = lv;
}

// ---------------------------------------------------------------------------
// K5: output GEMM. A read pre-combined/pre-split from Ahi/Alo (f16), pure
// vector loads; out[m,j] = sum_k A[m,k]*Wproj[j,k], fp32 out.
// ---------------------------------------------------------------------------
__global__ __launch_bounds__(256) void out_gemm(
        const _Float16* __restrict__ Ahi, const _Float16* __restrict__ Alo,
        const _Float16* __restrict__ Wh, const _Float16* __restrict__ Wl,
        float* __restrict__ outF)
{
    __shared__ __attribute__((aligned(16))) _Float16 Wsh[2][2][4096];  // 32 KB
    const int t = threadIdx.x, w = t >> 6, lane = t & 63;
    const int m16 = lane & 15, quad = lane >> 4;
    const int bm = blockIdx.x << 7, bn = blockIdx.y << 6;
    const int r0 = bm + (w << 5) + m16, r1 = r0 + 16;
    const int krow = lane >> 3, kblk = (lane & 7) ^ (krow & 7);
    const int e = m16 & 7;
    const int s00 = (quad ^ e) << 3, s01 = ((4 + quad) ^ e) << 3;
    const f32x4_t z = {0.f, 0.f, 0.f, 0.f};
    f32x4_t acc[2][4];
    #pragma unroll
    for (int rs = 0; rs < 2; rs++)
        #pragma unroll
        for (int tl = 0; tl < 4; tl++) acc[rs][tl] = z;

    auto stageW = [&](int buf, int kc) {
        #pragma unroll
        for (int ci = 0; ci < 4; ci++) {
            const int pp = (w << 2) + ci;
            const int s = pp >> 3, pj = pp & 7;
            const _Float16* src = (s ? Wl : Wh)
                + (size_t)(bn + (pj << 3) + krow) * C_ + kc + (kblk << 3);
            gload_lds16(src, &Wsh[buf][s][pj << 9]);
        }
    };
    auto loadA = [&](int ch, f16x8_t* d) {
        const int kc = ch << 6;                       // head = ch
        #pragma unroll
        for (int rs = 0; rs < 2; rs++) {
            const size_t base = ((size_t)(rs ? r1 : r0) << 9) + kc + (quad << 3);
            d[rs * 4 + 0] = load_h8(Ahi + base);
            d[rs * 4 + 1] = load_h8(Ahi + base + 32);
            d[rs * 4 + 2] = load_h8(Alo + base);
            d[rs * 4 + 3] = load_h8(Alo + base + 32);
        }
    };

    f16x8_t cA[8], nA[8];
    stageW(0, 0);
    loadA(0, cA);
    for (int ch = 0; ch < 8; ch++) {
        __syncthreads();
        if (ch + 1 < 8) {
            stageW((ch + 1) & 1, (ch + 1) << 6);
            loadA(ch + 1, nA);
        }
        const _Float16* W0 = Wsh[ch & 1][0];
        const _Float16* W1 = Wsh[ch & 1][1];
        #pragma unroll
        for (int tl = 0; tl < 4; tl++) {
            const int j64 = ((tl << 4) + m16) << 6;
            const f16x8_t bh0 = load_h8(&W0[j64 + s00]);
            const f16x8_t bh1 = load_h8(&W0[j64 + s01]);
            const f16x8_t bl0 = load_h8(&W1[j64 + s00]);
            const f16x8_t bl1 = load_h8(&W1[j64 + s01]);
            f32x4_t c0 = acc[0][tl];
            c0 = MFMAH(cA[0], bh0, c0); c0 = MFMAH(cA[1], bh1, c0);
            c0 = MFMAH(cA[2], bh0, c0); c0 = MFMAH(cA[3], bh1, c0);
            c0 = MFMAH(cA[0], bl0, c0); c0 = MFMAH(cA[1], bl1, c0);
            acc[0][tl] = c0;
            f32x4_t c1 = acc[1][tl];
            c1 = MFMAH(cA[4], bh0, c1); c1 = MFMAH(cA[5], bh1, c1);
            c1 = MFMAH(cA[6], bh0, c1); c1 = MFMAH(cA[7], bh1, c1);
            c1 = MFMAH(cA[4], bl0, c1); c1 = MFMAH(cA[5], bl1, c1);
            acc[1][tl] = c1;
        }
        #pragma unroll
        for (int i = 0; i < 8; i++) cA[i] = nA[i];
    }
    #pragma unroll
    for (int rs = 0; rs < 2; rs++) {
        #pragma unroll
        for (int tl = 0; tl < 4; tl++) {
            #pragma unroll
            for (int r = 0; r < 4; r++) {
                const int gr = bm + (w << 5) + (rs << 4) + (quad << 2) + r;
                const int gj = bn + (tl << 4) + m16;
                outF[(size_t)gr * C_ + gj] = acc[rs][tl][r];
            }
        }
    }
}

// ---------------------------------------------------------------------------
extern "C" void kernel_launch(void* const* d_in, const int* in_sizes, int n_in,
                              void* d_out, int out_size, void* d_ws, size_t ws_size,
                              hipStream_t stream) {
    const float* q  = (const float*)d_in[0];
    const float* k  = (const float*)d_in[1];
    const float* v  = (const float*)d_in[2];
    const float* supp_valid = (const float*)d_in[3];
    const int*   supp_mask  = (const int*)d_in[4];
    const float* Wq = (const float*)d_in[5];
    const float* Wk = (const float*)d_in[6];
    const float* Wv = (const float*)d_in[7];
    const float* Wp = (const float*)d_in[8];
    float* out = (float*)d_out;

    char* p = (char*)d_ws;
    _Float16* qhi = (_Float16*)p;      p += 4194304;   // [bh][n][d] f16 splits
    _Float16* qlo = (_Float16*)p;      p += 4194304;
    _Float16* khi = (_Float16*)p;      p += 4194304;
    _Float16* klo = (_Float16*)p;      p += 4194304;
    _Float16* vT  = (_Float16*)p;      p += 4194304;   // [bh] chunk-tiled (k')
    float* xp     = (float*)p;         p += 33554432;  // [4][4096][512] f32
    _Float16* wH  = (_Float16*)p;      p += 2097152;   // [4][512*512]
    _Float16* wL  = (_Float16*)p;      p += 2097152;
    _Float16* Ahi = (_Float16*)p;      p += 4194304;   // [4096][512] f16
    _Float16* Alo = (_Float16*)p;      p += 4194304;
    unsigned long long* q2kP = (unsigned long long*)p; p += 262144;
    unsigned long long* k2qP = (unsigned long long*)p; p += 262144;
    float* lp = (float*)p;             p += 524288;    // [4][16][2048]

    (void)hipMemsetAsync(q2kP, 0, 524288, stream);     // rowP + colP zero init

    dim3 bG(256);
    wsplit4<<<dim3(256, 4), bG, 0, stream>>>(Wq, Wk, Wv, Wp, wH, wL);
    proj_gemm<<<dim3(32, 8, 3), bG, 0, stream>>>(q, k, v, wH, wL,
                                                 qhi, qlo, khi, klo, vT);

    argmax_mfma<<<1024, bG, 0, stream>>>(qhi, qlo, khi, klo, q2kP, k2qP);

    attn_pv<<<1024, bG, 0, stream>>>(qhi, khi, vT, q2kP, k2qP,
                                     supp_mask, supp_valid, xp, lp);

    combine4<<<1024, bG, 0, stream>>>(xp, lp, Ahi, Alo);

    out_gemm<<<dim3(32, 8), bG, 0, stream>>>(Ahi, Alo,
                                             wH + 3 * 262144, wL + 3 * 262144, out);
}